// Round 6
// baseline (44179.758 us; speedup 1.0000x reference)
//
#include <hip/hip_runtime.h>
#include <hip/hip_bf16.h>

// MoD transformer block: B=4, T=4096, D=1024, H=16, HD=64, CAP=512, DFF=2730
// Inputs: float32. OUTPUT: float32 (per reference dtype — r3-r5 wrote bf16
// into an fp32 buffer; this round's single change). Naive GEMM/attention
// retained from r5 as the correctness baseline.

#define B_   4
#define T_   4096
#define D_   1024
#define H_   16
#define HD_  64
#define CAP_ 512
#define DFF_ 2730
#define M_   (B_*CAP_)   // 2048 selected rows total

__device__ __forceinline__ float bf2f(unsigned short u) {
    union { float f; unsigned int i; } v; v.i = ((unsigned int)u) << 16; return v.f;
}
__device__ __forceinline__ unsigned short f2bf(float f) {
    union { float f; unsigned int i; } v; v.f = f;
    unsigned int r = v.i + 0x7fffu + ((v.i >> 16) & 1u);   // RNE
    return (unsigned short)(r >> 16);
}

// ---------------- out = x pass-through (fp32 copy) ----------------
__global__ __launch_bounds__(256) void k_copyf(const float4* __restrict__ s,
                                               float4* __restrict__ d, int n4) {
    int i = blockIdx.x * 256 + threadIdx.x;
    int st = gridDim.x * 256;
    for (; i < n4; i += st) d[i] = s[i];
}

// ---------------- router scores: one wave per token row ----------------
__global__ __launch_bounds__(256) void k_router(const float* __restrict__ x,
                                                const float* __restrict__ wr,
                                                float* __restrict__ sc) {
    int gw   = (blockIdx.x * 256 + threadIdx.x) >> 6;   // 0..B*T-1
    int lane = threadIdx.x & 63;
    const float* row = x + (size_t)gw * D_;
    float s = 0.f;
#pragma unroll
    for (int p = 0; p < 4; ++p) {
        int c = p * 256 + lane * 4;
        float4 xv = *(const float4*)(row + c);
        float4 wv = *(const float4*)(wr + c);
        s += xv.x * wv.x + xv.y * wv.y + xv.z * wv.z + xv.w * wv.w;
    }
#pragma unroll
    for (int o = 32; o; o >>= 1) s += __shfl_xor(s, o);
    if (lane == 0) sc[gw] = s;
}

// ---------------- exact top-k: bitonic sort 4096 keys per batch ----------------
// key = (~sortable(score))<<32 | index  => ascending sort = desc score, asc index
__global__ __launch_bounds__(1024) void k_topk(const float* __restrict__ sc,
                                               int* __restrict__ idx) {
    __shared__ unsigned long long keys[T_];
    const float* s = sc + (size_t)blockIdx.x * T_;
    for (int i = threadIdx.x; i < T_; i += 1024) {
        union { float f; unsigned int u; } v; v.f = s[i];
        unsigned int k = (v.u & 0x80000000u) ? ~v.u : (v.u | 0x80000000u);
        k = ~k;
        keys[i] = ((unsigned long long)k << 32) | (unsigned int)i;
    }
    __syncthreads();
    for (int kk = 2; kk <= T_; kk <<= 1) {
        for (int j = kk >> 1; j > 0; j >>= 1) {
            for (int i = threadIdx.x; i < T_; i += 1024) {
                int ixj = i ^ j;
                if (ixj > i) {
                    unsigned long long a = keys[i], b = keys[ixj];
                    bool up = ((i & kk) == 0);
                    if ((a > b) == up) { keys[i] = b; keys[ixj] = a; }
                }
            }
            __syncthreads();
        }
    }
    for (int i = threadIdx.x; i < CAP_; i += 1024)
        idx[blockIdx.x * CAP_ + i] = (int)(keys[i] & 0xffffffffu);
}

// ---------------- gather + RMSNorm(g1) -> h (bf16) ----------------
__global__ __launch_bounds__(256) void k_gather_rms(const float* __restrict__ x,
                                                    const int* __restrict__ idx,
                                                    const float* __restrict__ g,
                                                    unsigned short* __restrict__ h) {
    int r = blockIdx.x;                 // 0..M_-1
    int b = r >> 9;                     // /CAP_
    int src = idx[r] & (T_ - 1);
    const float* xr = x + ((size_t)b * T_ + src) * D_;
    int c = threadIdx.x * 4;
    float4 xv = *(const float4*)(xr + c);
    float ss = xv.x*xv.x + xv.y*xv.y + xv.z*xv.z + xv.w*xv.w;
#pragma unroll
    for (int o = 32; o; o >>= 1) ss += __shfl_xor(ss, o);
    __shared__ float red[4];
    int lane = threadIdx.x & 63, w = threadIdx.x >> 6;
    if (lane == 0) red[w] = ss;
    __syncthreads();
    float tot = red[0] + red[1] + red[2] + red[3];
    float scale = rsqrtf(tot * (1.f / D_) + 1e-6f);
    float4 gv = *(const float4*)(g + c);
    ushort4 hv;
    hv.x = f2bf(xv.x * scale * gv.x);
    hv.y = f2bf(xv.y * scale * gv.y);
    hv.z = f2bf(xv.z * scale * gv.z);
    hv.w = f2bf(xv.w * scale * gv.w);
    *(ushort4*)(h + (size_t)r * D_ + c) = hv;
}

// ---------------- NAIVE GEMM: C[2048,N] = A[2048,K](bf16) * B[N,K]^T(fp32) ----------------
// One thread per C element, scalar K loop, fp32 accumulate.
// EPI==1: C = silu(U) * acc (SwiGLU fuse; U may alias C — 1:1 thread:element).
template<int EPI>
__global__ __launch_bounds__(256) void k_gemm_naive(const unsigned short* __restrict__ A,
                                                    const float* __restrict__ Bf,
                                                    unsigned short* __restrict__ C,
                                                    const unsigned short* __restrict__ U,
                                                    int Nr, int Kr) {
    int m = blockIdx.x * 16 + (threadIdx.x >> 4);
    int n = blockIdx.y * 16 + (threadIdx.x & 15);
    if (n >= Nr) return;
    const unsigned short* a = A + (size_t)m * Kr;
    const float*          b = Bf + (size_t)n * Kr;
    float acc = 0.f;
    for (int k = 0; k < Kr; ++k) acc += bf2f(a[k]) * b[k];
    size_t ci = (size_t)m * Nr + n;
    if (EPI == 1) {
        float uv = bf2f(U[ci]);
        float sl = uv / (1.f + __expf(-uv));
        C[ci] = f2bf(sl * acc);
    } else {
        C[ci] = f2bf(acc);
    }
}

// ---------------- NAIVE causal attention: two-pass exact softmax ----------------
// One wave per (b,h,q); lane = head-dim element.
__global__ __launch_bounds__(256) void k_attn(const unsigned short* __restrict__ qkv,
                                              unsigned short* __restrict__ o) {
    int gw   = (blockIdx.x * 256 + threadIdx.x) >> 6;   // 0..B*H*CAP-1
    int lane = threadIdx.x & 63;
    int bh = gw >> 9;          // /CAP_
    int q  = gw & 511;
    int b  = bh >> 4, h = bh & 15;
    const unsigned short* base = qkv + (size_t)b * CAP_ * 3 * D_;
    float qd = bf2f(base[(size_t)q * 3 * D_ + h * HD_ + lane]);
    const unsigned short* kbase = base + D_     + h * HD_ + lane;
    const unsigned short* vbase = base + 2 * D_ + h * HD_ + lane;
    // pass 1: row max
    float mx = -3.0e38f;
    for (int j = 0; j <= q; ++j) {
        float p = qd * bf2f(kbase[(size_t)j * 3 * D_]);
#pragma unroll
        for (int t = 32; t; t >>= 1) p += __shfl_xor(p, t);
        mx = fmaxf(mx, p * 0.125f);
    }
    // pass 2: exp-sum and weighted V
    float l = 0.f, acc = 0.f;
    for (int j = 0; j <= q; ++j) {
        float p = qd * bf2f(kbase[(size_t)j * 3 * D_]);
#pragma unroll
        for (int t = 32; t; t >>= 1) p += __shfl_xor(p, t);
        float e = __expf(p * 0.125f - mx);
        l += e;
        acc += e * bf2f(vbase[(size_t)j * 3 * D_]);
    }
    o[((size_t)(b * CAP_ + q)) * D_ + h * HD_ + lane] = f2bf(acc / l);
}

// ---------------- y = x_sel + xattn; h2 = rmsnorm(y, g2) ----------------
__global__ __launch_bounds__(256) void k_add_rms(const float* __restrict__ x,
                                                 const int* __restrict__ idx,
                                                 const unsigned short* __restrict__ xattn,
                                                 const float* __restrict__ g,
                                                 unsigned short* __restrict__ y,
                                                 unsigned short* __restrict__ h) {
    int r = blockIdx.x;
    int b = r >> 9;
    int src = idx[r] & (T_ - 1);
    int c = threadIdx.x * 4;
    const float* xr = x + ((size_t)b * T_ + src) * D_;
    float4 xv = *(const float4*)(xr + c);
    size_t off = (size_t)r * D_ + c;
    ushort4 a4 = *(const ushort4*)(xattn + off);
    float v0 = xv.x + bf2f(a4.x);
    float v1 = xv.y + bf2f(a4.y);
    float v2 = xv.z + bf2f(a4.z);
    float v3 = xv.w + bf2f(a4.w);
    float ss = v0*v0 + v1*v1 + v2*v2 + v3*v3;
#pragma unroll
    for (int o = 32; o; o >>= 1) ss += __shfl_xor(ss, o);
    __shared__ float red[4];
    int lane = threadIdx.x & 63, w = threadIdx.x >> 6;
    if (lane == 0) red[w] = ss;
    __syncthreads();
    float tot = red[0] + red[1] + red[2] + red[3];
    float scale = rsqrtf(tot * (1.f / D_) + 1e-6f);
    ushort4 yv;
    yv.x = f2bf(v0); yv.y = f2bf(v1); yv.z = f2bf(v2); yv.w = f2bf(v3);
    *(ushort4*)(y + off) = yv;
    float4 gv = *(const float4*)(g + c);
    ushort4 hv;
    hv.x = f2bf(v0 * scale * gv.x);
    hv.y = f2bf(v1 * scale * gv.y);
    hv.z = f2bf(v2 * scale * gv.z);
    hv.w = f2bf(v3 * scale * gv.w);
    *(ushort4*)(h + off) = hv;
}

// ---------------- scatter: out[b, idx, :] = y + xff  (fp32 out) ----------------
__global__ __launch_bounds__(256) void k_scatter(const unsigned short* __restrict__ y,
                                                 const unsigned short* __restrict__ xff,
                                                 const int* __restrict__ idx,
                                                 float* __restrict__ out) {
    int r = blockIdx.x;
    int b = r >> 9;
    int dst = idx[r] & (T_ - 1);
    int c = threadIdx.x * 4;
    size_t src = (size_t)r * D_ + c;
    ushort4 a4 = *(const ushort4*)(y + src);
    ushort4 f4 = *(const ushort4*)(xff + src);
    float4 o4;
    o4.x = bf2f(a4.x) + bf2f(f4.x);
    o4.y = bf2f(a4.y) + bf2f(f4.y);
    o4.z = bf2f(a4.z) + bf2f(f4.z);
    o4.w = bf2f(a4.w) + bf2f(f4.w);
    *(float4*)(out + ((size_t)b * T_ + dst) * D_ + c) = o4;
}

extern "C" void kernel_launch(void* const* d_in, const int* in_sizes, int n_in,
                              void* d_out, int out_size, void* d_ws, size_t ws_size,
                              hipStream_t stream) {
    const float* x     = (const float*)d_in[0];
    const float* w_rt  = (const float*)d_in[1];
    const float* W_qkv = (const float*)d_in[2];
    const float* W_out = (const float*)d_in[3];
    const float* g1    = (const float*)d_in[4];
    const float* g2    = (const float*)d_in[5];
    const float* W1    = (const float*)d_in[6];
    const float* W2    = (const float*)d_in[7];
    const float* W3    = (const float*)d_in[8];
    float* out = (float*)d_out;

    // ---- workspace: 25.3 MiB total (identical to r4/r5) ----
    char* p = (char*)d_ws;
    float* scores = (float*)p;
    int*   idx    = (int*)(p + 65536);
    size_t off = 131072;
    unsigned short* R1 = (unsigned short*)(p + off); off += (size_t)M_*3*D_*2;   // 12.58M
    unsigned short* R2 = (unsigned short*)(p + off); off += (size_t)M_*D_*2;     // 4.19M
    unsigned short* R3 = (unsigned short*)(p + off); off += (size_t)M_*D_*2;     // 4.19M
    unsigned short* R4 = (unsigned short*)(p + off); off += (size_t)M_*D_*2;     // 4.19M

    unsigned short* h1    = R2;
    unsigned short* qkvb  = R1;
    unsigned short* attno = R2;   // after h1 dead
    unsigned short* xattn = R3;
    unsigned short* ybuf  = R4;
    unsigned short* h2b   = R2;   // after attno dead
    unsigned short* ubuf  = R1;   // after qkvb dead
    unsigned short* xffb  = R3;   // after xattn dead

    // 1. out = x  (fp32 pass-through; selected rows overwritten by scatter)
    k_copyf<<<2048, 256, 0, stream>>>((const float4*)x, (float4*)out, (B_*T_*D_) / 4);
    // 2. router scores
    k_router<<<(B_*T_) / 4, 256, 0, stream>>>(x, w_rt, scores);
    // 3. exact top-k
    k_topk<<<B_, 1024, 0, stream>>>(scores, idx);
    // 4. gather + rmsnorm(g1) -> h1 (bf16)
    k_gather_rms<<<M_, 256, 0, stream>>>(x, idx, g1, h1);
    // 5. qkv = h1 @ W_qkv^T   [2048 x 3072], K=1024
    k_gemm_naive<0><<<dim3(M_/16, (3*D_)/16), 256, 0, stream>>>(h1, W_qkv, qkvb, nullptr, 3*D_, D_);
    // 6. attention (naive two-pass)
    k_attn<<<(B_*H_*CAP_) / 4, 256, 0, stream>>>(qkvb, attno);
    // 7. x_attn = o @ W_out^T  [2048 x 1024], K=1024
    k_gemm_naive<0><<<dim3(M_/16, D_/16), 256, 0, stream>>>(attno, W_out, xattn, nullptr, D_, D_);
    // 8. y = x_sel + xattn; h2 = rmsnorm(y, g2)
    k_add_rms<<<M_, 256, 0, stream>>>(x, idx, xattn, g2, ybuf, h2b);
    // 9. u = h2 @ W1^T  [2048 x 2730], K=1024
    k_gemm_naive<0><<<dim3(M_/16, (DFF_+15)/16), 256, 0, stream>>>(h2b, W1, ubuf, nullptr, DFF_, D_);
    // 10. f = silu(u) * (h2 @ W2^T)  — fused epilogue, in-place into ubuf
    k_gemm_naive<1><<<dim3(M_/16, (DFF_+15)/16), 256, 0, stream>>>(h2b, W2, ubuf, ubuf, DFF_, D_);
    // 11. x_ff = f @ W3^T   [2048 x 1024], K=2730
    k_gemm_naive<0><<<dim3(M_/16, D_/16), 256, 0, stream>>>(ubuf, W3, xffb, nullptr, D_, DFF_);
    // 12. out[b, idx, :] = y + x_ff  (fp32)
    k_scatter<<<M_, 256, 0, stream>>>(ybuf, xffb, idx, out);
}

// Round 7
// 1988.551 us; speedup vs baseline: 22.2171x; 22.2171x over previous
//
#include <hip/hip_runtime.h>
#include <hip/hip_bf16.h>

// MoD transformer block: B=4, T=4096, D=1024, H=16, HD=64, CAP=512, DFF=2730
// Inputs fp32, output fp32. Round 7: MFMA GEMM reintroduced (r6 naive GEMM
// was 4x11.3ms, VALUBusy 5.9% — latency-bound). Naive attention retained.

#define B_   4
#define T_   4096
#define D_   1024
#define H_   16
#define HD_  64
#define CAP_ 512
#define DFF_ 2730
#define M_   (B_*CAP_)   // 2048 selected rows total

typedef __attribute__((ext_vector_type(8))) short          s16x8;
typedef __attribute__((ext_vector_type(8))) unsigned short u16x8;
typedef __attribute__((ext_vector_type(4))) float          f32x4;

__device__ __forceinline__ float bf2f(unsigned short u) {
    union { float f; unsigned int i; } v; v.i = ((unsigned int)u) << 16; return v.f;
}
__device__ __forceinline__ unsigned short f2bf(float f) {
    union { float f; unsigned int i; } v; v.f = f;
    unsigned int r = v.i + 0x7fffu + ((v.i >> 16) & 1u);   // RNE
    return (unsigned short)(r >> 16);
}

// ---------------- out = x pass-through (fp32 copy) ----------------
__global__ __launch_bounds__(256) void k_copyf(const float4* __restrict__ s,
                                               float4* __restrict__ d, int n4) {
    int i = blockIdx.x * 256 + threadIdx.x;
    int st = gridDim.x * 256;
    for (; i < n4; i += st) d[i] = s[i];
}

// ---------------- router scores: one wave per token row ----------------
__global__ __launch_bounds__(256) void k_router(const float* __restrict__ x,
                                                const float* __restrict__ wr,
                                                float* __restrict__ sc) {
    int gw   = (blockIdx.x * 256 + threadIdx.x) >> 6;   // 0..B*T-1
    int lane = threadIdx.x & 63;
    const float* row = x + (size_t)gw * D_;
    float s = 0.f;
#pragma unroll
    for (int p = 0; p < 4; ++p) {
        int c = p * 256 + lane * 4;
        float4 xv = *(const float4*)(row + c);
        float4 wv = *(const float4*)(wr + c);
        s += xv.x * wv.x + xv.y * wv.y + xv.z * wv.z + xv.w * wv.w;
    }
#pragma unroll
    for (int o = 32; o; o >>= 1) s += __shfl_xor(s, o);
    if (lane == 0) sc[gw] = s;
}

// ---------------- exact top-k: bitonic sort 4096 keys per batch ----------------
// key = (~sortable(score))<<32 | index  => ascending sort = desc score, asc index
__global__ __launch_bounds__(1024) void k_topk(const float* __restrict__ sc,
                                               int* __restrict__ idx) {
    __shared__ unsigned long long keys[T_];
    const float* s = sc + (size_t)blockIdx.x * T_;
    for (int i = threadIdx.x; i < T_; i += 1024) {
        union { float f; unsigned int u; } v; v.f = s[i];
        unsigned int k = (v.u & 0x80000000u) ? ~v.u : (v.u | 0x80000000u);
        k = ~k;
        keys[i] = ((unsigned long long)k << 32) | (unsigned int)i;
    }
    __syncthreads();
    for (int kk = 2; kk <= T_; kk <<= 1) {
        for (int j = kk >> 1; j > 0; j >>= 1) {
            for (int i = threadIdx.x; i < T_; i += 1024) {
                int ixj = i ^ j;
                if (ixj > i) {
                    unsigned long long a = keys[i], b = keys[ixj];
                    bool up = ((i & kk) == 0);
                    if ((a > b) == up) { keys[i] = b; keys[ixj] = a; }
                }
            }
            __syncthreads();
        }
    }
    for (int i = threadIdx.x; i < CAP_; i += 1024)
        idx[blockIdx.x * CAP_ + i] = (int)(keys[i] & 0xffffffffu);
}

// ---------------- gather + RMSNorm(g1) -> h (bf16) ----------------
__global__ __launch_bounds__(256) void k_gather_rms(const float* __restrict__ x,
                                                    const int* __restrict__ idx,
                                                    const float* __restrict__ g,
                                                    unsigned short* __restrict__ h) {
    int r = blockIdx.x;                 // 0..M_-1
    int b = r >> 9;                     // /CAP_
    int src = idx[r] & (T_ - 1);
    const float* xr = x + ((size_t)b * T_ + src) * D_;
    int c = threadIdx.x * 4;
    float4 xv = *(const float4*)(xr + c);
    float ss = xv.x*xv.x + xv.y*xv.y + xv.z*xv.z + xv.w*xv.w;
#pragma unroll
    for (int o = 32; o; o >>= 1) ss += __shfl_xor(ss, o);
    __shared__ float red[4];
    int lane = threadIdx.x & 63, w = threadIdx.x >> 6;
    if (lane == 0) red[w] = ss;
    __syncthreads();
    float tot = red[0] + red[1] + red[2] + red[3];
    float scale = rsqrtf(tot * (1.f / D_) + 1e-6f);
    float4 gv = *(const float4*)(g + c);
    ushort4 hv;
    hv.x = f2bf(xv.x * scale * gv.x);
    hv.y = f2bf(xv.y * scale * gv.y);
    hv.z = f2bf(xv.z * scale * gv.z);
    hv.w = f2bf(xv.w * scale * gv.w);
    *(ushort4*)(h + (size_t)r * D_ + c) = hv;
}

// ---------------- MFMA GEMM: C[2048,N] = A[2048,K](bf16) * B[N,K]^T(fp32) ----------------
// B (weights) converted fp32->bf16 during LDS staging (float2 = 8B-aligned for
// any even K). EPI==1: C = silu(U) * acc (SwiGLU fuse; U may alias C — each
// element touched by exactly one thread, read-before-write within thread).
// 64x64 tile, BK=32, 4 waves, mfma_f32_16x16x32_bf16.
template<int EPI>
__global__ __launch_bounds__(256) void k_gemm(const unsigned short* __restrict__ A,
                                              const float* __restrict__ Bf,
                                              unsigned short* __restrict__ C,
                                              const unsigned short* __restrict__ U,
                                              int Nr, int Kr) {
    __shared__ __align__(16) unsigned short As[64][40];  // pad 40: 2-way banks (free)
    __shared__ __align__(16) unsigned short Bs[64][40];
    int m0 = blockIdx.x * 64;
    int n0 = blockIdx.y * 64;
    int t = threadIdx.x;
    int w = t >> 6, lane = t & 63;
    int lr = lane & 15, lk = (lane >> 4) * 8;
    int sr = t >> 2, scol = (t & 3) * 8;
    bool vec8 = ((Kr & 7) == 0);

    f32x4 zero = {0.f, 0.f, 0.f, 0.f};
    f32x4 acc[4] = {zero, zero, zero, zero};

    int nk = (Kr + 31) >> 5;
    for (int kt = 0; kt < nk; ++kt) {
        int k0 = kt << 5;
        // stage A tile (bf16; M=2048 % 64 == 0 so rows in-bounds)
        {
            size_t rowb = (size_t)(m0 + sr) * Kr;
            if (vec8) {   // K%8==0: 16B-aligned full vector, in-bounds
                *(u16x8*)&As[sr][scol] = *(const u16x8*)(A + rowb + k0 + scol);
            } else {      // K even (2730): 4B-aligned ushort2, K-guarded
#pragma unroll
                for (int tt = 0; tt < 4; ++tt) {
                    int col = k0 + scol + 2 * tt;
                    ushort2 v2_ = (col < Kr) ? *(const ushort2*)(A + rowb + col)
                                             : make_ushort2(0, 0);
                    *(ushort2*)&As[sr][scol + 2 * tt] = v2_;
                }
            }
        }
        // stage B tile (fp32 -> bf16; guard N rows and K cols)
        {
            if (n0 + sr < Nr) {
                size_t rowb = (size_t)(n0 + sr) * Kr;
#pragma unroll
                for (int tt = 0; tt < 4; ++tt) {
                    int col = k0 + scol + 2 * tt;
                    float2 v2_ = (col < Kr) ? *(const float2*)(Bf + rowb + col)
                                            : make_float2(0.f, 0.f);
                    Bs[sr][scol + 2 * tt]     = f2bf(v2_.x);
                    Bs[sr][scol + 2 * tt + 1] = f2bf(v2_.y);
                }
            } else {
#pragma unroll
                for (int j = 0; j < 8; ++j) Bs[sr][scol + j] = 0;
            }
        }
        __syncthreads();
        s16x8 af = *(const s16x8*)&As[(w << 4) + lr][lk];
#pragma unroll
        for (int s_ = 0; s_ < 4; ++s_) {
            s16x8 bf = *(const s16x8*)&Bs[(s_ << 4) + lr][lk];
            acc[s_] = __builtin_amdgcn_mfma_f32_16x16x32_bf16(af, bf, acc[s_], 0, 0, 0);
        }
        __syncthreads();
    }
    // C/D layout: col = lane&15, row = (lane>>4)*4 + i  [measured m89]
    int orow = m0 + (w << 4) + ((lane >> 4) << 2);
    int ocol0 = n0 + lr;
#pragma unroll
    for (int s_ = 0; s_ < 4; ++s_) {
        int col = ocol0 + (s_ << 4);
        if (col < Nr) {
#pragma unroll
            for (int i = 0; i < 4; ++i) {
                size_t ci = (size_t)(orow + i) * Nr + col;
                if (EPI == 1) {
                    float uv = bf2f(U[ci]);
                    float sl = uv / (1.f + __expf(-uv));
                    C[ci] = f2bf(sl * acc[s_][i]);
                } else {
                    C[ci] = f2bf(acc[s_][i]);
                }
            }
        }
    }
}

// ---------------- NAIVE causal attention: two-pass exact softmax ----------------
// One wave per (b,h,q); lane = head-dim element.
__global__ __launch_bounds__(256) void k_attn(const unsigned short* __restrict__ qkv,
                                              unsigned short* __restrict__ o) {
    int gw   = (blockIdx.x * 256 + threadIdx.x) >> 6;   // 0..B*H*CAP-1
    int lane = threadIdx.x & 63;
    int bh = gw >> 9;          // /CAP_
    int q  = gw & 511;
    int b  = bh >> 4, h = bh & 15;
    const unsigned short* base = qkv + (size_t)b * CAP_ * 3 * D_;
    float qd = bf2f(base[(size_t)q * 3 * D_ + h * HD_ + lane]);
    const unsigned short* kbase = base + D_     + h * HD_ + lane;
    const unsigned short* vbase = base + 2 * D_ + h * HD_ + lane;
    // pass 1: row max
    float mx = -3.0e38f;
    for (int j = 0; j <= q; ++j) {
        float p = qd * bf2f(kbase[(size_t)j * 3 * D_]);
#pragma unroll
        for (int t = 32; t; t >>= 1) p += __shfl_xor(p, t);
        mx = fmaxf(mx, p * 0.125f);
    }
    // pass 2: exp-sum and weighted V
    float l = 0.f, acc = 0.f;
    for (int j = 0; j <= q; ++j) {
        float p = qd * bf2f(kbase[(size_t)j * 3 * D_]);
#pragma unroll
        for (int t = 32; t; t >>= 1) p += __shfl_xor(p, t);
        float e = __expf(p * 0.125f - mx);
        l += e;
        acc += e * bf2f(vbase[(size_t)j * 3 * D_]);
    }
    o[((size_t)(b * CAP_ + q)) * D_ + h * HD_ + lane] = f2bf(acc / l);
}

// ---------------- y = x_sel + xattn; h2 = rmsnorm(y, g2) ----------------
__global__ __launch_bounds__(256) void k_add_rms(const float* __restrict__ x,
                                                 const int* __restrict__ idx,
                                                 const unsigned short* __restrict__ xattn,
                                                 const float* __restrict__ g,
                                                 unsigned short* __restrict__ y,
                                                 unsigned short* __restrict__ h) {
    int r = blockIdx.x;
    int b = r >> 9;
    int src = idx[r] & (T_ - 1);
    int c = threadIdx.x * 4;
    const float* xr = x + ((size_t)b * T_ + src) * D_;
    float4 xv = *(const float4*)(xr + c);
    size_t off = (size_t)r * D_ + c;
    ushort4 a4 = *(const ushort4*)(xattn + off);
    float v0 = xv.x + bf2f(a4.x);
    float v1 = xv.y + bf2f(a4.y);
    float v2 = xv.z + bf2f(a4.z);
    float v3 = xv.w + bf2f(a4.w);
    float ss = v0*v0 + v1*v1 + v2*v2 + v3*v3;
#pragma unroll
    for (int o = 32; o; o >>= 1) ss += __shfl_xor(ss, o);
    __shared__ float red[4];
    int lane = threadIdx.x & 63, w = threadIdx.x >> 6;
    if (lane == 0) red[w] = ss;
    __syncthreads();
    float tot = red[0] + red[1] + red[2] + red[3];
    float scale = rsqrtf(tot * (1.f / D_) + 1e-6f);
    ushort4 yv;
    yv.x = f2bf(v0); yv.y = f2bf(v1); yv.z = f2bf(v2); yv.w = f2bf(v3);
    *(ushort4*)(y + off) = yv;
    float4 gv = *(const float4*)(g + c);
    ushort4 hv;
    hv.x = f2bf(v0 * scale * gv.x);
    hv.y = f2bf(v1 * scale * gv.y);
    hv.z = f2bf(v2 * scale * gv.z);
    hv.w = f2bf(v3 * scale * gv.w);
    *(ushort4*)(h + off) = hv;
}

// ---------------- scatter: out[b, idx, :] = y + xff  (fp32 out) ----------------
__global__ __launch_bounds__(256) void k_scatter(const unsigned short* __restrict__ y,
                                                 const unsigned short* __restrict__ xff,
                                                 const int* __restrict__ idx,
                                                 float* __restrict__ out) {
    int r = blockIdx.x;
    int b = r >> 9;
    int dst = idx[r] & (T_ - 1);
    int c = threadIdx.x * 4;
    size_t src = (size_t)r * D_ + c;
    ushort4 a4 = *(const ushort4*)(y + src);
    ushort4 f4 = *(const ushort4*)(xff + src);
    float4 o4;
    o4.x = bf2f(a4.x) + bf2f(f4.x);
    o4.y = bf2f(a4.y) + bf2f(f4.y);
    o4.z = bf2f(a4.z) + bf2f(f4.z);
    o4.w = bf2f(a4.w) + bf2f(f4.w);
    *(float4*)(out + ((size_t)b * T_ + dst) * D_ + c) = o4;
}

extern "C" void kernel_launch(void* const* d_in, const int* in_sizes, int n_in,
                              void* d_out, int out_size, void* d_ws, size_t ws_size,
                              hipStream_t stream) {
    const float* x     = (const float*)d_in[0];
    const float* w_rt  = (const float*)d_in[1];
    const float* W_qkv = (const float*)d_in[2];
    const float* W_out = (const float*)d_in[3];
    const float* g1    = (const float*)d_in[4];
    const float* g2    = (const float*)d_in[5];
    const float* W1    = (const float*)d_in[6];
    const float* W2    = (const float*)d_in[7];
    const float* W3    = (const float*)d_in[8];
    float* out = (float*)d_out;

    // ---- workspace: 25.3 MiB total (identical to r4-r6) ----
    char* p = (char*)d_ws;
    float* scores = (float*)p;
    int*   idx    = (int*)(p + 65536);
    size_t off = 131072;
    unsigned short* R1 = (unsigned short*)(p + off); off += (size_t)M_*3*D_*2;   // 12.58M
    unsigned short* R2 = (unsigned short*)(p + off); off += (size_t)M_*D_*2;     // 4.19M
    unsigned short* R3 = (unsigned short*)(p + off); off += (size_t)M_*D_*2;     // 4.19M
    unsigned short* R4 = (unsigned short*)(p + off); off += (size_t)M_*D_*2;     // 4.19M

    unsigned short* h1    = R2;
    unsigned short* qkvb  = R1;
    unsigned short* attno = R2;   // after h1 dead
    unsigned short* xattn = R3;
    unsigned short* ybuf  = R4;
    unsigned short* h2b   = R2;   // after attno dead
    unsigned short* ubuf  = R1;   // after qkvb dead
    unsigned short* xffb  = R3;   // after xattn dead

    // 1. out = x  (fp32 pass-through; selected rows overwritten by scatter)
    k_copyf<<<2048, 256, 0, stream>>>((const float4*)x, (float4*)out, (B_*T_*D_) / 4);
    // 2. router scores
    k_router<<<(B_*T_) / 4, 256, 0, stream>>>(x, w_rt, scores);
    // 3. exact top-k
    k_topk<<<B_, 1024, 0, stream>>>(scores, idx);
    // 4. gather + rmsnorm(g1) -> h1 (bf16)
    k_gather_rms<<<M_, 256, 0, stream>>>(x, idx, g1, h1);
    // 5. qkv = h1 @ W_qkv^T   [2048 x 3072], K=1024
    k_gemm<0><<<dim3(M_/64, 3*D_/64), 256, 0, stream>>>(h1, W_qkv, qkvb, nullptr, 3*D_, D_);
    // 6. attention (naive two-pass)
    k_attn<<<(B_*H_*CAP_) / 4, 256, 0, stream>>>(qkvb, attno);
    // 7. x_attn = o @ W_out^T  [2048 x 1024], K=1024
    k_gemm<0><<<dim3(M_/64, D_/64), 256, 0, stream>>>(attno, W_out, xattn, nullptr, D_, D_);
    // 8. y = x_sel + xattn; h2 = rmsnorm(y, g2)
    k_add_rms<<<M_, 256, 0, stream>>>(x, idx, xattn, g2, ybuf, h2b);
    // 9. u = h2 @ W1^T  [2048 x 2730], K=1024
    k_gemm<0><<<dim3(M_/64, (DFF_+63)/64), 256, 0, stream>>>(h2b, W1, ubuf, nullptr, DFF_, D_);
    // 10. f = silu(u) * (h2 @ W2^T)  — fused epilogue, in-place into ubuf
    k_gemm<1><<<dim3(M_/64, (DFF_+63)/64), 256, 0, stream>>>(h2b, W2, ubuf, ubuf, DFF_, D_);
    // 11. x_ff = f @ W3^T   [2048 x 1024], K=2730
    k_gemm<0><<<dim3(M_/64, D_/64), 256, 0, stream>>>(ubuf, W3, xffb, nullptr, D_, DFF_);
    // 12. out[b, idx, :] = y + x_ff  (fp32)
    k_scatter<<<M_, 256, 0, stream>>>(ybuf, xffb, idx, out);
}

// Round 10
// 595.424 us; speedup vs baseline: 74.1988x; 3.3397x over previous
//
#include <hip/hip_runtime.h>
#include <hip/hip_bf16.h>

// MoD transformer block: B=4, T=4096, D=1024, H=16, HD=64, CAP=512, DFF=2730
// Inputs fp32, output fp32. Round 10: fix k_attn_mfma LDS K-tile width —
// Ks was [32][40] (copied from GEMM BK-shape) but attention K-tile is
// [32 kv][64 hd]: staging (cols up to 63) overflowed rows. Now [32][72].

#define B_   4
#define T_   4096
#define D_   1024
#define H_   16
#define HD_  64
#define CAP_ 512
#define DFF_ 2730
#define M_   (B_*CAP_)   // 2048 selected rows total

typedef __attribute__((ext_vector_type(8))) short          s16x8;
typedef __attribute__((ext_vector_type(8))) unsigned short u16x8;
typedef __attribute__((ext_vector_type(4))) float          f32x4;

__device__ __forceinline__ float bf2f(unsigned short u) {
    union { float f; unsigned int i; } v; v.i = ((unsigned int)u) << 16; return v.f;
}
__device__ __forceinline__ unsigned short f2bf(float f) {
    union { float f; unsigned int i; } v; v.f = f;
    unsigned int r = v.i + 0x7fffu + ((v.i >> 16) & 1u);   // RNE
    return (unsigned short)(r >> 16);
}

// ---------------- out = x pass-through (fp32 copy) ----------------
__global__ __launch_bounds__(256) void k_copyf(const float4* __restrict__ s,
                                               float4* __restrict__ d, int n4) {
    int i = blockIdx.x * 256 + threadIdx.x;
    int st = gridDim.x * 256;
    for (; i < n4; i += st) d[i] = s[i];
}

// ---------------- router scores: one wave per token row ----------------
__global__ __launch_bounds__(256) void k_router(const float* __restrict__ x,
                                                const float* __restrict__ wr,
                                                float* __restrict__ sc) {
    int gw   = (blockIdx.x * 256 + threadIdx.x) >> 6;   // 0..B*T-1
    int lane = threadIdx.x & 63;
    const float* row = x + (size_t)gw * D_;
    float s = 0.f;
#pragma unroll
    for (int p = 0; p < 4; ++p) {
        int c = p * 256 + lane * 4;
        float4 xv = *(const float4*)(row + c);
        float4 wv = *(const float4*)(wr + c);
        s += xv.x * wv.x + xv.y * wv.y + xv.z * wv.z + xv.w * wv.w;
    }
#pragma unroll
    for (int o = 32; o; o >>= 1) s += __shfl_xor(s, o);
    if (lane == 0) sc[gw] = s;
}

// ---------------- exact top-k: bitonic sort 4096 keys per batch ----------------
__global__ __launch_bounds__(1024) void k_topk(const float* __restrict__ sc,
                                               int* __restrict__ idx) {
    __shared__ unsigned long long keys[T_];
    const float* s = sc + (size_t)blockIdx.x * T_;
    for (int i = threadIdx.x; i < T_; i += 1024) {
        union { float f; unsigned int u; } v; v.f = s[i];
        unsigned int k = (v.u & 0x80000000u) ? ~v.u : (v.u | 0x80000000u);
        k = ~k;
        keys[i] = ((unsigned long long)k << 32) | (unsigned int)i;
    }
    __syncthreads();
    for (int kk = 2; kk <= T_; kk <<= 1) {
        for (int j = kk >> 1; j > 0; j >>= 1) {
            for (int i = threadIdx.x; i < T_; i += 1024) {
                int ixj = i ^ j;
                if (ixj > i) {
                    unsigned long long a = keys[i], b = keys[ixj];
                    bool up = ((i & kk) == 0);
                    if ((a > b) == up) { keys[i] = b; keys[ixj] = a; }
                }
            }
            __syncthreads();
        }
    }
    for (int i = threadIdx.x; i < CAP_; i += 1024)
        idx[blockIdx.x * CAP_ + i] = (int)(keys[i] & 0xffffffffu);
}

// ---------------- gather + RMSNorm(g1) -> h (bf16) ----------------
__global__ __launch_bounds__(256) void k_gather_rms(const float* __restrict__ x,
                                                    const int* __restrict__ idx,
                                                    const float* __restrict__ g,
                                                    unsigned short* __restrict__ h) {
    int r = blockIdx.x;                 // 0..M_-1
    int b = r >> 9;                     // /CAP_
    int src = idx[r] & (T_ - 1);
    const float* xr = x + ((size_t)b * T_ + src) * D_;
    int c = threadIdx.x * 4;
    float4 xv = *(const float4*)(xr + c);
    float ss = xv.x*xv.x + xv.y*xv.y + xv.z*xv.z + xv.w*xv.w;
#pragma unroll
    for (int o = 32; o; o >>= 1) ss += __shfl_xor(ss, o);
    __shared__ float red[4];
    int lane = threadIdx.x & 63, w = threadIdx.x >> 6;
    if (lane == 0) red[w] = ss;
    __syncthreads();
    float tot = red[0] + red[1] + red[2] + red[3];
    float scale = rsqrtf(tot * (1.f / D_) + 1e-6f);
    float4 gv = *(const float4*)(g + c);
    ushort4 hv;
    hv.x = f2bf(xv.x * scale * gv.x);
    hv.y = f2bf(xv.y * scale * gv.y);
    hv.z = f2bf(xv.z * scale * gv.z);
    hv.w = f2bf(xv.w * scale * gv.w);
    *(ushort4*)(h + (size_t)r * D_ + c) = hv;
}

// ---------------- MFMA GEMM: C[2048,N] = A[2048,K](bf16) * B[N,K]^T(fp32) ----------------
template<int EPI>
__global__ __launch_bounds__(256) void k_gemm(const unsigned short* __restrict__ A,
                                              const float* __restrict__ Bf,
                                              unsigned short* __restrict__ C,
                                              const unsigned short* __restrict__ U,
                                              int Nr, int Kr) {
    __shared__ __align__(16) unsigned short As[64][40];  // pad 40: 2-way banks (free)
    __shared__ __align__(16) unsigned short Bs[64][40];
    int m0 = blockIdx.x * 64;
    int n0 = blockIdx.y * 64;
    int t = threadIdx.x;
    int w = t >> 6, lane = t & 63;
    int lr = lane & 15, lk = (lane >> 4) * 8;
    int sr = t >> 2, scol = (t & 3) * 8;
    bool vec8 = ((Kr & 7) == 0);

    f32x4 zero = {0.f, 0.f, 0.f, 0.f};
    f32x4 acc[4] = {zero, zero, zero, zero};

    int nk = (Kr + 31) >> 5;
    for (int kt = 0; kt < nk; ++kt) {
        int k0 = kt << 5;
        {
            size_t rowb = (size_t)(m0 + sr) * Kr;
            if (vec8) {
                *(u16x8*)&As[sr][scol] = *(const u16x8*)(A + rowb + k0 + scol);
            } else {
#pragma unroll
                for (int tt = 0; tt < 4; ++tt) {
                    int col = k0 + scol + 2 * tt;
                    ushort2 v2_ = (col < Kr) ? *(const ushort2*)(A + rowb + col)
                                             : make_ushort2(0, 0);
                    *(ushort2*)&As[sr][scol + 2 * tt] = v2_;
                }
            }
        }
        {
            if (n0 + sr < Nr) {
                size_t rowb = (size_t)(n0 + sr) * Kr;
#pragma unroll
                for (int tt = 0; tt < 4; ++tt) {
                    int col = k0 + scol + 2 * tt;
                    float2 v2_ = (col < Kr) ? *(const float2*)(Bf + rowb + col)
                                            : make_float2(0.f, 0.f);
                    Bs[sr][scol + 2 * tt]     = f2bf(v2_.x);
                    Bs[sr][scol + 2 * tt + 1] = f2bf(v2_.y);
                }
            } else {
#pragma unroll
                for (int j = 0; j < 8; ++j) Bs[sr][scol + j] = 0;
            }
        }
        __syncthreads();
        s16x8 af = *(const s16x8*)&As[(w << 4) + lr][lk];
#pragma unroll
        for (int s_ = 0; s_ < 4; ++s_) {
            s16x8 bf = *(const s16x8*)&Bs[(s_ << 4) + lr][lk];
            acc[s_] = __builtin_amdgcn_mfma_f32_16x16x32_bf16(af, bf, acc[s_], 0, 0, 0);
        }
        __syncthreads();
    }
    int orow = m0 + (w << 4) + ((lane >> 4) << 2);
    int ocol0 = n0 + lr;
#pragma unroll
    for (int s_ = 0; s_ < 4; ++s_) {
        int col = ocol0 + (s_ << 4);
        if (col < Nr) {
#pragma unroll
            for (int i = 0; i < 4; ++i) {
                size_t ci = (size_t)(orow + i) * Nr + col;
                if (EPI == 1) {
                    float uv = bf2f(U[ci]);
                    float sl = uv / (1.f + __expf(-uv));
                    C[ci] = f2bf(sl * acc[s_][i]);
                } else {
                    C[ci] = f2bf(acc[s_][i]);
                }
            }
        }
    }
}

// ---------------- MFMA flash attention (causal, gathered order) ----------------
// One workgroup per (qtile=64, head, batch); 4 waves x 16 q-rows.
// Ks[32 kv][72]: 64 head-dims + 8 pad (r8/r9 bug: width 40 overflowed).
// Vt[64 d][40]: 32 kv + 8 pad. Ps[wave][16 q][40]: 32 kv + 8 pad.
__global__ __launch_bounds__(256) void k_attn_mfma(const unsigned short* __restrict__ qkv,
                                                   unsigned short* __restrict__ o) {
    __shared__ __align__(16) unsigned short Ks[32][72];     // [kv][hd 0..63]
    __shared__ __align__(16) unsigned short Vt[64][40];     // [d][kv 0..31]
    __shared__ __align__(16) unsigned short Ps[4][16][40];  // per-wave P [q][kv]
    int qt = blockIdx.x, h = blockIdx.y, b = blockIdx.z;
    int q0 = qt * 64;
    int t = threadIdx.x, w = t >> 6, lane = t & 63;
    int lr = lane & 15, lg = lane >> 4;
    const unsigned short* base = qkv + (size_t)b * CAP_ * 3 * D_;

    // Q A-fragments for this wave (rows q0+16w+lr), two hd-halves
    int qrow = q0 + w * 16 + lr;
    const unsigned short* qp = base + (size_t)qrow * 3 * D_ + h * 64;
    s16x8 aq0 = *(const s16x8*)(qp + lg * 8);
    s16x8 aq1 = *(const s16x8*)(qp + 32 + lg * 8);

    f32x4 zero = {0.f, 0.f, 0.f, 0.f};
    f32x4 oacc[4] = {zero, zero, zero, zero};
    float m_[4], l_[4];
#pragma unroll
    for (int i = 0; i < 4; ++i) { m_[i] = -3.0e38f; l_[i] = 0.f; }

    int qbase = q0 + w * 16 + lg * 4;      // + i = absolute q row of C-frag
    int ntile = (q0 + 64) >> 5;            // kv tiles to stage

    int skv = t >> 3, sc = (t & 7) * 8;    // staging coords: kv 0..31, col 0..56
    for (int kt = 0; kt < ntile; ++kt) {
        int kv0 = kt << 5;
        // ---- cooperative stage: Ks[32][64], Vt[64][32] ----
        {
            const unsigned short* kr = base + (size_t)(kv0 + skv) * 3 * D_ + D_     + h * 64 + sc;
            const unsigned short* vr = base + (size_t)(kv0 + skv) * 3 * D_ + 2 * D_ + h * 64 + sc;
            *(u16x8*)&Ks[skv][sc] = *(const u16x8*)kr;
            u16x8 vv = *(const u16x8*)vr;
#pragma unroll
            for (int j = 0; j < 8; ++j) Vt[sc + j][skv] = vv[j];
        }
        __syncthreads();
        // ---- QK^T: S[16q][32kv] as two C-frags (all waves, unconditional) ----
        f32x4 s0 = zero, s1 = zero;
        s16x8 k00 = *(const s16x8*)&Ks[lr][lg * 8];
        s16x8 k01 = *(const s16x8*)&Ks[lr][32 + lg * 8];
        s16x8 k10 = *(const s16x8*)&Ks[16 + lr][lg * 8];
        s16x8 k11 = *(const s16x8*)&Ks[16 + lr][32 + lg * 8];
        s0 = __builtin_amdgcn_mfma_f32_16x16x32_bf16(aq0, k00, s0, 0, 0, 0);
        s0 = __builtin_amdgcn_mfma_f32_16x16x32_bf16(aq1, k01, s0, 0, 0, 0);
        s1 = __builtin_amdgcn_mfma_f32_16x16x32_bf16(aq0, k10, s1, 0, 0, 0);
        s1 = __builtin_amdgcn_mfma_f32_16x16x32_bf16(aq1, k11, s1, 0, 0, 0);
        // ---- scale + causal mask (kv > q) ----
#pragma unroll
        for (int i = 0; i < 4; ++i) {
            float v0 = s0[i] * 0.125f, v1 = s1[i] * 0.125f;
            if (kv0 + lr      > qbase + i) v0 = -3.0e38f;
            if (kv0 + 16 + lr > qbase + i) v1 = -3.0e38f;
            s0[i] = v0; s1[i] = v1;
        }
        // ---- online softmax: row max over 32 kv ----
        float pm[4];
#pragma unroll
        for (int i = 0; i < 4; ++i) pm[i] = fmaxf(s0[i], s1[i]);
#pragma unroll
        for (int d = 1; d < 16; d <<= 1) {
#pragma unroll
            for (int i = 0; i < 4; ++i) pm[i] = fmaxf(pm[i], __shfl_xor(pm[i], d));
        }
        float p0[4], p1[4], ps[4], scl[4];
#pragma unroll
        for (int i = 0; i < 4; ++i) {
            float mn = fmaxf(m_[i], pm[i]);
            scl[i] = __expf(m_[i] - mn);
            p0[i] = __expf(s0[i] - mn);
            p1[i] = __expf(s1[i] - mn);
            ps[i] = p0[i] + p1[i];
            m_[i] = mn;
        }
#pragma unroll
        for (int d = 1; d < 16; d <<= 1) {
#pragma unroll
            for (int i = 0; i < 4; ++i) ps[i] += __shfl_xor(ps[i], d);
        }
#pragma unroll
        for (int i = 0; i < 4; ++i) l_[i] = l_[i] * scl[i] + ps[i];
        // rescale O
#pragma unroll
        for (int dg = 0; dg < 4; ++dg)
#pragma unroll
            for (int i = 0; i < 4; ++i) oacc[dg][i] *= scl[i];
        // ---- P -> bf16 -> per-wave LDS; barrier; read as A-fragment ----
#pragma unroll
        for (int i = 0; i < 4; ++i) {
            Ps[w][lg * 4 + i][lr]      = f2bf(p0[i]);
            Ps[w][lg * 4 + i][16 + lr] = f2bf(p1[i]);
        }
        __syncthreads();
        s16x8 pa = *(const s16x8*)&Ps[w][lr][lg * 8];
        // ---- PV: O[16q][64d] += P[16,32] * V[32,64] ----
#pragma unroll
        for (int dg = 0; dg < 4; ++dg) {
            s16x8 vf = *(const s16x8*)&Vt[dg * 16 + lr][lg * 8];
            oacc[dg] = __builtin_amdgcn_mfma_f32_16x16x32_bf16(pa, vf, oacc[dg], 0, 0, 0);
        }
        __syncthreads();
    }
    // ---- epilogue: O / l -> attno ----
    unsigned short* orow = o + ((size_t)(b * CAP_ + qbase)) * D_ + h * 64;
#pragma unroll
    for (int i = 0; i < 4; ++i) {
        float inv = 1.f / l_[i];
#pragma unroll
        for (int dg = 0; dg < 4; ++dg)
            orow[(size_t)i * D_ + dg * 16 + lr] = f2bf(oacc[dg][i] * inv);
    }
}

// ---------------- y = x_sel + xattn; h2 = rmsnorm(y, g2) ----------------
__global__ __launch_bounds__(256) void k_add_rms(const float* __restrict__ x,
                                                 const int* __restrict__ idx,
                                                 const unsigned short* __restrict__ xattn,
                                                 const float* __restrict__ g,
                                                 unsigned short* __restrict__ y,
                                                 unsigned short* __restrict__ h) {
    int r = blockIdx.x;
    int b = r >> 9;
    int src = idx[r] & (T_ - 1);
    int c = threadIdx.x * 4;
    const float* xr = x + ((size_t)b * T_ + src) * D_;
    float4 xv = *(const float4*)(xr + c);
    size_t off = (size_t)r * D_ + c;
    ushort4 a4 = *(const ushort4*)(xattn + off);
    float v0 = xv.x + bf2f(a4.x);
    float v1 = xv.y + bf2f(a4.y);
    float v2 = xv.z + bf2f(a4.z);
    float v3 = xv.w + bf2f(a4.w);
    float ss = v0*v0 + v1*v1 + v2*v2 + v3*v3;
#pragma unroll
    for (int o = 32; o; o >>= 1) ss += __shfl_xor(ss, o);
    __shared__ float red[4];
    int lane = threadIdx.x & 63, w = threadIdx.x >> 6;
    if (lane == 0) red[w] = ss;
    __syncthreads();
    float tot = red[0] + red[1] + red[2] + red[3];
    float scale = rsqrtf(tot * (1.f / D_) + 1e-6f);
    ushort4 yv;
    yv.x = f2bf(v0); yv.y = f2bf(v1); yv.z = f2bf(v2); yv.w = f2bf(v3);
    *(ushort4*)(y + off) = yv;
    float4 gv = *(const float4*)(g + c);
    ushort4 hv;
    hv.x = f2bf(v0 * scale * gv.x);
    hv.y = f2bf(v1 * scale * gv.y);
    hv.z = f2bf(v2 * scale * gv.z);
    hv.w = f2bf(v3 * scale * gv.w);
    *(ushort4*)(h + off) = hv;
}

// ---------------- scatter: out[b, idx, :] = y + xff  (fp32 out) ----------------
__global__ __launch_bounds__(256) void k_scatter(const unsigned short* __restrict__ y,
                                                 const unsigned short* __restrict__ xff,
                                                 const int* __restrict__ idx,
                                                 float* __restrict__ out) {
    int r = blockIdx.x;
    int b = r >> 9;
    int dst = idx[r] & (T_ - 1);
    int c = threadIdx.x * 4;
    size_t src = (size_t)r * D_ + c;
    ushort4 a4 = *(const ushort4*)(y + src);
    ushort4 f4 = *(const ushort4*)(xff + src);
    float4 o4;
    o4.x = bf2f(a4.x) + bf2f(f4.x);
    o4.y = bf2f(a4.y) + bf2f(f4.y);
    o4.z = bf2f(a4.z) + bf2f(f4.z);
    o4.w = bf2f(a4.w) + bf2f(f4.w);
    *(float4*)(out + ((size_t)b * T_ + dst) * D_ + c) = o4;
}

extern "C" void kernel_launch(void* const* d_in, const int* in_sizes, int n_in,
                              void* d_out, int out_size, void* d_ws, size_t ws_size,
                              hipStream_t stream) {
    const float* x     = (const float*)d_in[0];
    const float* w_rt  = (const float*)d_in[1];
    const float* W_qkv = (const float*)d_in[2];
    const float* W_out = (const float*)d_in[3];
    const float* g1    = (const float*)d_in[4];
    const float* g2    = (const float*)d_in[5];
    const float* W1    = (const float*)d_in[6];
    const float* W2    = (const float*)d_in[7];
    const float* W3    = (const float*)d_in[8];
    float* out = (float*)d_out;

    // ---- workspace: 25.3 MiB total (identical to r4-r9) ----
    char* p = (char*)d_ws;
    float* scores = (float*)p;
    int*   idx    = (int*)(p + 65536);
    size_t off = 131072;
    unsigned short* R1 = (unsigned short*)(p + off); off += (size_t)M_*3*D_*2;   // 12.58M
    unsigned short* R2 = (unsigned short*)(p + off); off += (size_t)M_*D_*2;     // 4.19M
    unsigned short* R3 = (unsigned short*)(p + off); off += (size_t)M_*D_*2;     // 4.19M
    unsigned short* R4 = (unsigned short*)(p + off); off += (size_t)M_*D_*2;     // 4.19M

    unsigned short* h1    = R2;
    unsigned short* qkvb  = R1;
    unsigned short* attno = R2;   // after h1 dead
    unsigned short* xattn = R3;
    unsigned short* ybuf  = R4;
    unsigned short* h2b   = R2;   // after attno dead
    unsigned short* ubuf  = R1;   // after qkvb dead
    unsigned short* xffb  = R3;   // after xattn dead

    // 1. out = x  (fp32 pass-through; selected rows overwritten by scatter)
    k_copyf<<<2048, 256, 0, stream>>>((const float4*)x, (float4*)out, (B_*T_*D_) / 4);
    // 2. router scores
    k_router<<<(B_*T_) / 4, 256, 0, stream>>>(x, w_rt, scores);
    // 3. exact top-k
    k_topk<<<B_, 1024, 0, stream>>>(scores, idx);
    // 4. gather + rmsnorm(g1) -> h1 (bf16)
    k_gather_rms<<<M_, 256, 0, stream>>>(x, idx, g1, h1);
    // 5. qkv = h1 @ W_qkv^T   [2048 x 3072], K=1024
    k_gemm<0><<<dim3(M_/64, 3*D_/64), 256, 0, stream>>>(h1, W_qkv, qkvb, nullptr, 3*D_, D_);
    // 6. MFMA flash attention
    k_attn_mfma<<<dim3(CAP_/64, H_, B_), 256, 0, stream>>>(qkvb, attno);
    // 7. x_attn = o @ W_out^T  [2048 x 1024], K=1024
    k_gemm<0><<<dim3(M_/64, D_/64), 256, 0, stream>>>(attno, W_out, xattn, nullptr, D_, D_);
    // 8. y = x_sel + xattn; h2 = rmsnorm(y, g2)
    k_add_rms<<<M_, 256, 0, stream>>>(x, idx, xattn, g2, ybuf, h2b);
    // 9. u = h2 @ W1^T  [2048 x 2730], K=1024
    k_gemm<0><<<dim3(M_/64, (DFF_+63)/64), 256, 0, stream>>>(h2b, W1, ubuf, nullptr, DFF_, D_);
    // 10. f = silu(u) * (h2 @ W2^T)  — fused epilogue, in-place into ubuf
    k_gemm<1><<<dim3(M_/64, (DFF_+63)/64), 256, 0, stream>>>(h2b, W2, ubuf, ubuf, DFF_, D_);
    // 11. x_ff = f @ W3^T   [2048 x 1024], K=2730
    k_gemm<0><<<dim3(M_/64, D_/64), 256, 0, stream>>>(ubuf, W3, xffb, nullptr, D_, DFF_);
    // 12. out[b, idx, :] = y + x_ff  (fp32)
    k_scatter<<<M_, 256, 0, stream>>>(ybuf, xffb, idx, out);
}

// Round 12
// 388.762 us; speedup vs baseline: 113.6422x; 1.5316x over previous
//
#include <hip/hip_runtime.h>
#include <hip/hip_bf16.h>

// MoD transformer block: B=4, T=4096, D=1024, H=16, HD=64, CAP=512, DFF=2730
// Inputs fp32, output fp32. Round 12: same as round 11 (128x128 GEMM,
// pre-converted bf16 weights, K padded to 2752) with the epilogue typo fixed
// (acc[mi][ni][i], not acc[mi][ni]).

#define B_   4
#define T_   4096
#define D_   1024
#define H_   16
#define HD_  64
#define CAP_ 512
#define DFF_ 2730
#define DFFP 2752               // DFF padded to mult of 32 (and 8) for vec8 K-path
#define M_   (B_*CAP_)          // 2048 selected rows total

typedef __attribute__((ext_vector_type(8))) short          s16x8;
typedef __attribute__((ext_vector_type(8))) unsigned short u16x8;
typedef __attribute__((ext_vector_type(4))) float          f32x4;

__device__ __forceinline__ float bf2f(unsigned short u) {
    union { float f; unsigned int i; } v; v.i = ((unsigned int)u) << 16; return v.f;
}
__device__ __forceinline__ unsigned short f2bf(float f) {
    union { float f; unsigned int i; } v; v.f = f;
    unsigned int r = v.i + 0x7fffu + ((v.i >> 16) & 1u);   // RNE
    return (unsigned short)(r >> 16);
}

// ---------------- out = x pass-through (fp32 copy) ----------------
__global__ __launch_bounds__(256) void k_copyf(const float4* __restrict__ s,
                                               float4* __restrict__ d, int n4) {
    int i = blockIdx.x * 256 + threadIdx.x;
    int st = gridDim.x * 256;
    for (; i < n4; i += st) d[i] = s[i];
}

// ---------------- fp32 -> bf16 flat convert ----------------
__global__ __launch_bounds__(256) void k_f2b(const float4* __restrict__ s,
                                             ushort4* __restrict__ d, int n4) {
    int i = blockIdx.x * 256 + threadIdx.x;
    int st = gridDim.x * 256;
    for (; i < n4; i += st) {
        float4 v = s[i];
        ushort4 o;
        o.x = f2bf(v.x); o.y = f2bf(v.y); o.z = f2bf(v.z); o.w = f2bf(v.w);
        d[i] = o;
    }
}

// ---------------- fp32 [rows][K] -> bf16 [rows][Kp], zero-padded cols ----------------
__global__ __launch_bounds__(256) void k_f2b_pad(const float* __restrict__ src,
                                                 unsigned short* __restrict__ dst,
                                                 int K, int Kp, int rows) {
    int g = blockIdx.x * 256 + threadIdx.x;
    int ng = rows * (Kp >> 3);
    int st = gridDim.x * 256;
    for (; g < ng; g += st) {
        int row = g / (Kp >> 3);
        int c = (g - row * (Kp >> 3)) << 3;
        const float* s = src + (size_t)row * K + c;
        u16x8 v;
        if (c + 8 <= K) {
#pragma unroll
            for (int j = 0; j < 4; ++j) {            // 8B-aligned (K,c even)
                float2 f = *(const float2*)(s + 2 * j);
                v[2*j] = f2bf(f.x); v[2*j+1] = f2bf(f.y);
            }
        } else {
#pragma unroll
            for (int j = 0; j < 8; ++j) v[j] = (c + j < K) ? f2bf(s[j]) : (unsigned short)0;
        }
        *(u16x8*)(dst + (size_t)row * Kp + c) = v;
    }
}

// ---------------- router scores: one wave per token row ----------------
__global__ __launch_bounds__(256) void k_router(const float* __restrict__ x,
                                                const float* __restrict__ wr,
                                                float* __restrict__ sc) {
    int gw   = (blockIdx.x * 256 + threadIdx.x) >> 6;   // 0..B*T-1
    int lane = threadIdx.x & 63;
    const float* row = x + (size_t)gw * D_;
    float s = 0.f;
#pragma unroll
    for (int p = 0; p < 4; ++p) {
        int c = p * 256 + lane * 4;
        float4 xv = *(const float4*)(row + c);
        float4 wv = *(const float4*)(wr + c);
        s += xv.x * wv.x + xv.y * wv.y + xv.z * wv.z + xv.w * wv.w;
    }
#pragma unroll
    for (int o = 32; o; o >>= 1) s += __shfl_xor(s, o);
    if (lane == 0) sc[gw] = s;
}

// ---------------- exact top-k: bitonic sort 4096 keys per batch ----------------
__global__ __launch_bounds__(1024) void k_topk(const float* __restrict__ sc,
                                               int* __restrict__ idx) {
    __shared__ unsigned long long keys[T_];
    const float* s = sc + (size_t)blockIdx.x * T_;
    for (int i = threadIdx.x; i < T_; i += 1024) {
        union { float f; unsigned int u; } v; v.f = s[i];
        unsigned int k = (v.u & 0x80000000u) ? ~v.u : (v.u | 0x80000000u);
        k = ~k;
        keys[i] = ((unsigned long long)k << 32) | (unsigned int)i;
    }
    __syncthreads();
    for (int kk = 2; kk <= T_; kk <<= 1) {
        for (int j = kk >> 1; j > 0; j >>= 1) {
            for (int i = threadIdx.x; i < T_; i += 1024) {
                int ixj = i ^ j;
                if (ixj > i) {
                    unsigned long long a = keys[i], b = keys[ixj];
                    bool up = ((i & kk) == 0);
                    if ((a > b) == up) { keys[i] = b; keys[ixj] = a; }
                }
            }
            __syncthreads();
        }
    }
    for (int i = threadIdx.x; i < CAP_; i += 1024)
        idx[blockIdx.x * CAP_ + i] = (int)(keys[i] & 0xffffffffu);
}

// ---------------- gather + RMSNorm(g1) -> h (bf16) ----------------
__global__ __launch_bounds__(256) void k_gather_rms(const float* __restrict__ x,
                                                    const int* __restrict__ idx,
                                                    const float* __restrict__ g,
                                                    unsigned short* __restrict__ h) {
    int r = blockIdx.x;                 // 0..M_-1
    int b = r >> 9;                     // /CAP_
    int src = idx[r] & (T_ - 1);
    const float* xr = x + ((size_t)b * T_ + src) * D_;
    int c = threadIdx.x * 4;
    float4 xv = *(const float4*)(xr + c);
    float ss = xv.x*xv.x + xv.y*xv.y + xv.z*xv.z + xv.w*xv.w;
#pragma unroll
    for (int o = 32; o; o >>= 1) ss += __shfl_xor(ss, o);
    __shared__ float red[4];
    int lane = threadIdx.x & 63, w = threadIdx.x >> 6;
    if (lane == 0) red[w] = ss;
    __syncthreads();
    float tot = red[0] + red[1] + red[2] + red[3];
    float scale = rsqrtf(tot * (1.f / D_) + 1e-6f);
    float4 gv = *(const float4*)(g + c);
    ushort4 hv;
    hv.x = f2bf(xv.x * scale * gv.x);
    hv.y = f2bf(xv.y * scale * gv.y);
    hv.z = f2bf(xv.z * scale * gv.z);
    hv.w = f2bf(xv.w * scale * gv.w);
    *(ushort4*)(h + (size_t)r * D_ + c) = hv;
}

// ---------------- MFMA GEMM 128x128: C[M,Nout] = A[M,Kr] * B[Nb,Kr]^T ----------------
// A, B both bf16 (B pre-converted). Kr % 32 == 0, rows 16B-aligned (Kr % 8 == 0).
// 4 waves in 2x2, each owns 64x64 via 4x4 16x16x32 fragments (16 MFMA/K-step).
// B rows >= Nb stage as zero (gives exact-zero pad cols in C when Nout > Nb).
// EPI==1: C = silu(U) * acc (U may alias C; 1:1 thread:element).
template<int EPI>
__global__ __launch_bounds__(256) void k_gemm128(const unsigned short* __restrict__ A,
                                                 const unsigned short* __restrict__ Bw,
                                                 unsigned short* __restrict__ C,
                                                 const unsigned short* __restrict__ U,
                                                 int Nout, int Nb, int Kr) {
    __shared__ __align__(16) unsigned short As[128][40];  // stride 80B: 2-way banks (free)
    __shared__ __align__(16) unsigned short Bs[128][40];
    int m0 = blockIdx.x * 128;
    int n0 = blockIdx.y * 128;
    int t = threadIdx.x;
    int w = t >> 6, lane = t & 63;
    int lr = lane & 15, lk = (lane >> 4) * 8;
    int wm = (w >> 1) * 64, wn = (w & 1) * 64;
    int sr = t >> 2, scol = (t & 3) * 8;      // staging: row t>>2 (+64), col (t&3)*8

    f32x4 acc[4][4];
#pragma unroll
    for (int mi = 0; mi < 4; ++mi)
#pragma unroll
        for (int ni = 0; ni < 4; ++ni) acc[mi][ni] = {0.f, 0.f, 0.f, 0.f};

    for (int k0 = 0; k0 < Kr; k0 += 32) {
        // stage A (M % 128 == 0: rows in-bounds)
#pragma unroll
        for (int r = 0; r < 2; ++r) {
            int row = r * 64 + sr;
            *(u16x8*)&As[row][scol] =
                *(const u16x8*)(A + (size_t)(m0 + row) * Kr + k0 + scol);
        }
        // stage B (guard Nb)
#pragma unroll
        for (int r = 0; r < 2; ++r) {
            int row = r * 64 + sr;
            u16x8 v = {0, 0, 0, 0, 0, 0, 0, 0};
            if (n0 + row < Nb)
                v = *(const u16x8*)(Bw + (size_t)(n0 + row) * Kr + k0 + scol);
            *(u16x8*)&Bs[row][scol] = v;
        }
        __syncthreads();
        s16x8 af[4], bf[4];
#pragma unroll
        for (int i = 0; i < 4; ++i) {
            af[i] = *(const s16x8*)&As[wm + i * 16 + lr][lk];
            bf[i] = *(const s16x8*)&Bs[wn + i * 16 + lr][lk];
        }
#pragma unroll
        for (int mi = 0; mi < 4; ++mi)
#pragma unroll
            for (int ni = 0; ni < 4; ++ni)
                acc[mi][ni] = __builtin_amdgcn_mfma_f32_16x16x32_bf16(af[mi], bf[ni],
                                                                      acc[mi][ni], 0, 0, 0);
        __syncthreads();
    }
    // C/D layout: row = (lane>>4)*4 + i, col = lane&15  [measured m89]
    int orow0 = m0 + wm + ((lane >> 4) << 2);
    int ocol0 = n0 + wn + lr;
#pragma unroll
    for (int ni = 0; ni < 4; ++ni) {
        int col = ocol0 + ni * 16;
        if (col < Nout) {
#pragma unroll
            for (int mi = 0; mi < 4; ++mi) {
#pragma unroll
                for (int i = 0; i < 4; ++i) {
                    size_t ci = (size_t)(orow0 + mi * 16 + i) * Nout + col;
                    if (EPI == 1) {
                        float uv = bf2f(U[ci]);
                        float sl = uv / (1.f + __expf(-uv));
                        C[ci] = f2bf(sl * acc[mi][ni][i]);
                    } else {
                        C[ci] = f2bf(acc[mi][ni][i]);
                    }
                }
            }
        }
    }
}

// ---------------- MFMA flash attention (causal, gathered order) ----------------
// One workgroup per (qtile=64, head, batch); 4 waves x 16 q-rows.
__global__ __launch_bounds__(256) void k_attn_mfma(const unsigned short* __restrict__ qkv,
                                                   unsigned short* __restrict__ o) {
    __shared__ __align__(16) unsigned short Ks[32][72];     // [kv][hd 0..63]
    __shared__ __align__(16) unsigned short Vt[64][40];     // [d][kv 0..31]
    __shared__ __align__(16) unsigned short Ps[4][16][40];  // per-wave P [q][kv]
    int qt = blockIdx.x, h = blockIdx.y, b = blockIdx.z;
    int q0 = qt * 64;
    int t = threadIdx.x, w = t >> 6, lane = t & 63;
    int lr = lane & 15, lg = lane >> 4;
    const unsigned short* base = qkv + (size_t)b * CAP_ * 3 * D_;

    int qrow = q0 + w * 16 + lr;
    const unsigned short* qp = base + (size_t)qrow * 3 * D_ + h * 64;
    s16x8 aq0 = *(const s16x8*)(qp + lg * 8);
    s16x8 aq1 = *(const s16x8*)(qp + 32 + lg * 8);

    f32x4 zero = {0.f, 0.f, 0.f, 0.f};
    f32x4 oacc[4] = {zero, zero, zero, zero};
    float m_[4], l_[4];
#pragma unroll
    for (int i = 0; i < 4; ++i) { m_[i] = -3.0e38f; l_[i] = 0.f; }

    int qbase = q0 + w * 16 + lg * 4;
    int ntile = (q0 + 64) >> 5;

    int skv = t >> 3, sc = (t & 7) * 8;
    for (int kt = 0; kt < ntile; ++kt) {
        int kv0 = kt << 5;
        {
            const unsigned short* kr = base + (size_t)(kv0 + skv) * 3 * D_ + D_     + h * 64 + sc;
            const unsigned short* vr = base + (size_t)(kv0 + skv) * 3 * D_ + 2 * D_ + h * 64 + sc;
            *(u16x8*)&Ks[skv][sc] = *(const u16x8*)kr;
            u16x8 vv = *(const u16x8*)vr;
#pragma unroll
            for (int j = 0; j < 8; ++j) Vt[sc + j][skv] = vv[j];
        }
        __syncthreads();
        f32x4 s0 = zero, s1 = zero;
        s16x8 k00 = *(const s16x8*)&Ks[lr][lg * 8];
        s16x8 k01 = *(const s16x8*)&Ks[lr][32 + lg * 8];
        s16x8 k10 = *(const s16x8*)&Ks[16 + lr][lg * 8];
        s16x8 k11 = *(const s16x8*)&Ks[16 + lr][32 + lg * 8];
        s0 = __builtin_amdgcn_mfma_f32_16x16x32_bf16(aq0, k00, s0, 0, 0, 0);
        s0 = __builtin_amdgcn_mfma_f32_16x16x32_bf16(aq1, k01, s0, 0, 0, 0);
        s1 = __builtin_amdgcn_mfma_f32_16x16x32_bf16(aq0, k10, s1, 0, 0, 0);
        s1 = __builtin_amdgcn_mfma_f32_16x16x32_bf16(aq1, k11, s1, 0, 0, 0);
#pragma unroll
        for (int i = 0; i < 4; ++i) {
            float v0 = s0[i] * 0.125f, v1 = s1[i] * 0.125f;
            if (kv0 + lr      > qbase + i) v0 = -3.0e38f;
            if (kv0 + 16 + lr > qbase + i) v1 = -3.0e38f;
            s0[i] = v0; s1[i] = v1;
        }
        float pm[4];
#pragma unroll
        for (int i = 0; i < 4; ++i) pm[i] = fmaxf(s0[i], s1[i]);
#pragma unroll
        for (int d = 1; d < 16; d <<= 1) {
#pragma unroll
            for (int i = 0; i < 4; ++i) pm[i] = fmaxf(pm[i], __shfl_xor(pm[i], d));
        }
        float p0[4], p1[4], ps[4], scl[4];
#pragma unroll
        for (int i = 0; i < 4; ++i) {
            float mn = fmaxf(m_[i], pm[i]);
            scl[i] = __expf(m_[i] - mn);
            p0[i] = __expf(s0[i] - mn);
            p1[i] = __expf(s1[i] - mn);
            ps[i] = p0[i] + p1[i];
            m_[i] = mn;
        }
#pragma unroll
        for (int d = 1; d < 16; d <<= 1) {
#pragma unroll
            for (int i = 0; i < 4; ++i) ps[i] += __shfl_xor(ps[i], d);
        }
#pragma unroll
        for (int i = 0; i < 4; ++i) l_[i] = l_[i] * scl[i] + ps[i];
#pragma unroll
        for (int dg = 0; dg < 4; ++dg)
#pragma unroll
            for (int i = 0; i < 4; ++i) oacc[dg][i] *= scl[i];
#pragma unroll
        for (int i = 0; i < 4; ++i) {
            Ps[w][lg * 4 + i][lr]      = f2bf(p0[i]);
            Ps[w][lg * 4 + i][16 + lr] = f2bf(p1[i]);
        }
        __syncthreads();
        s16x8 pa = *(const s16x8*)&Ps[w][lr][lg * 8];
#pragma unroll
        for (int dg = 0; dg < 4; ++dg) {
            s16x8 vf = *(const s16x8*)&Vt[dg * 16 + lr][lg * 8];
            oacc[dg] = __builtin_amdgcn_mfma_f32_16x16x32_bf16(pa, vf, oacc[dg], 0, 0, 0);
        }
        __syncthreads();
    }
    unsigned short* orow = o + ((size_t)(b * CAP_ + qbase)) * D_ + h * 64;
#pragma unroll
    for (int i = 0; i < 4; ++i) {
        float inv = 1.f / l_[i];
#pragma unroll
        for (int dg = 0; dg < 4; ++dg)
            orow[(size_t)i * D_ + dg * 16 + lr] = f2bf(oacc[dg][i] * inv);
    }
}

// ---------------- y = x_sel + xattn; h2 = rmsnorm(y, g2) ----------------
__global__ __launch_bounds__(256) void k_add_rms(const float* __restrict__ x,
                                                 const int* __restrict__ idx,
                                                 const unsigned short* __restrict__ xattn,
                                                 const float* __restrict__ g,
                                                 unsigned short* __restrict__ y,
                                                 unsigned short* __restrict__ h) {
    int r = blockIdx.x;
    int b = r >> 9;
    int src = idx[r] & (T_ - 1);
    int c = threadIdx.x * 4;
    const float* xr = x + ((size_t)b * T_ + src) * D_;
    float4 xv = *(const float4*)(xr + c);
    size_t off = (size_t)r * D_ + c;
    ushort4 a4 = *(const ushort4*)(xattn + off);
    float v0 = xv.x + bf2f(a4.x);
    float v1 = xv.y + bf2f(a4.y);
    float v2 = xv.z + bf2f(a4.z);
    float v3 = xv.w + bf2f(a4.w);
    float ss = v0*v0 + v1*v1 + v2*v2 + v3*v3;
#pragma unroll
    for (int o = 32; o; o >>= 1) ss += __shfl_xor(ss, o);
    __shared__ float red[4];
    int lane = threadIdx.x & 63, w = threadIdx.x >> 6;
    if (lane == 0) red[w] = ss;
    __syncthreads();
    float tot = red[0] + red[1] + red[2] + red[3];
    float scale = rsqrtf(tot * (1.f / D_) + 1e-6f);
    ushort4 yv;
    yv.x = f2bf(v0); yv.y = f2bf(v1); yv.z = f2bf(v2); yv.w = f2bf(v3);
    *(ushort4*)(y + off) = yv;
    float4 gv = *(const float4*)(g + c);
    ushort4 hv;
    hv.x = f2bf(v0 * scale * gv.x);
    hv.y = f2bf(v1 * scale * gv.y);
    hv.z = f2bf(v2 * scale * gv.z);
    hv.w = f2bf(v3 * scale * gv.w);
    *(ushort4*)(h + off) = hv;
}

// ---------------- scatter: out[b, idx, :] = y + xff  (fp32 out) ----------------
__global__ __launch_bounds__(256) void k_scatter(const unsigned short* __restrict__ y,
                                                 const unsigned short* __restrict__ xff,
                                                 const int* __restrict__ idx,
                                                 float* __restrict__ out) {
    int r = blockIdx.x;
    int b = r >> 9;
    int dst = idx[r] & (T_ - 1);
    int c = threadIdx.x * 4;
    size_t src = (size_t)r * D_ + c;
    ushort4 a4 = *(const ushort4*)(y + src);
    ushort4 f4 = *(const ushort4*)(xff + src);
    float4 o4;
    o4.x = bf2f(a4.x) + bf2f(f4.x);
    o4.y = bf2f(a4.y) + bf2f(f4.y);
    o4.z = bf2f(a4.z) + bf2f(f4.z);
    o4.w = bf2f(a4.w) + bf2f(f4.w);
    *(float4*)(out + ((size_t)b * T_ + dst) * D_ + c) = o4;
}

extern "C" void kernel_launch(void* const* d_in, const int* in_sizes, int n_in,
                              void* d_out, int out_size, void* d_ws, size_t ws_size,
                              hipStream_t stream) {
    const float* x     = (const float*)d_in[0];
    const float* w_rt  = (const float*)d_in[1];
    const float* W_qkv = (const float*)d_in[2];
    const float* W_out = (const float*)d_in[3];
    const float* g1    = (const float*)d_in[4];
    const float* g2    = (const float*)d_in[5];
    const float* W1    = (const float*)d_in[6];
    const float* W2    = (const float*)d_in[7];
    const float* W3    = (const float*)d_in[8];
    float* out = (float*)d_out;

    // ---- workspace: ~31.6 MiB ----
    char* p = (char*)d_ws;
    float* scores = (float*)p;
    int*   idx    = (int*)(p + 65536);
    size_t off = 131072;
    unsigned short* WBIG = (unsigned short*)(p + off); off += (size_t)3*D_*D_*2;   // 6.29M
    unsigned short* R1   = (unsigned short*)(p + off); off += (size_t)M_*3*D_*2;   // 12.58M
    unsigned short* R2   = (unsigned short*)(p + off); off += (size_t)M_*D_*2;     // 4.19M
    unsigned short* R3   = (unsigned short*)(p + off); off += (size_t)M_*D_*2;     // 4.19M
    unsigned short* R4   = (unsigned short*)(p + off); off += (size_t)M_*D_*2;     // 4.19M

    unsigned short* h1    = R2;
    unsigned short* qkvb  = R1;
    unsigned short* attno = R2;   // after h1 dead
    unsigned short* xattn = R3;
    unsigned short* ybuf  = R4;
    unsigned short* h2b   = R2;   // after attno dead
    unsigned short* ubuf  = R1;   // after qkvb dead; [2048][DFFP]
    unsigned short* xffb  = R3;   // after xattn dead

    // 1. out = x  (fp32 pass-through; selected rows overwritten by scatter)
    k_copyf<<<2048, 256, 0, stream>>>((const float4*)x, (float4*)out, (B_*T_*D_) / 4);
    // 2. router scores
    k_router<<<(B_*T_) / 4, 256, 0, stream>>>(x, w_rt, scores);
    // 3. exact top-k
    k_topk<<<B_, 1024, 0, stream>>>(scores, idx);
    // 4. gather + rmsnorm(g1) -> h1 (bf16)
    k_gather_rms<<<M_, 256, 0, stream>>>(x, idx, g1, h1);
    // 5. qkv = h1 @ W_qkv^T   [2048 x 3072], K=1024
    k_f2b<<<2048, 256, 0, stream>>>((const float4*)W_qkv, (ushort4*)WBIG, (3*D_*D_) / 4);
    k_gemm128<0><<<dim3(M_/128, 3*D_/128), 256, 0, stream>>>(h1, WBIG, qkvb, nullptr,
                                                             3*D_, 3*D_, D_);
    // 6. MFMA flash attention
    k_attn_mfma<<<dim3(CAP_/64, H_, B_), 256, 0, stream>>>(qkvb, attno);
    // 7. x_attn = o @ W_out^T  [2048 x 1024], K=1024
    k_f2b<<<1024, 256, 0, stream>>>((const float4*)W_out, (ushort4*)WBIG, (D_*D_) / 4);
    k_gemm128<0><<<dim3(M_/128, D_/128), 256, 0, stream>>>(attno, WBIG, xattn, nullptr,
                                                           D_, D_, D_);
    // 8. y = x_sel + xattn; h2 = rmsnorm(y, g2)
    k_add_rms<<<M_, 256, 0, stream>>>(x, idx, xattn, g2, ybuf, h2b);
    // 9. u = h2 @ W1^T  -> ubuf [2048][DFFP], cols DFF..DFFP-1 exact zero
    k_f2b<<<2048, 256, 0, stream>>>((const float4*)W1, (ushort4*)WBIG, (DFF_*D_) / 4);
    k_gemm128<0><<<dim3(M_/128, (DFFP+127)/128), 256, 0, stream>>>(h2b, WBIG, ubuf, nullptr,
                                                                   DFFP, DFF_, D_);
    // 10. f = silu(u) * (h2 @ W2^T)  — fused epilogue, in-place into ubuf
    k_f2b<<<2048, 256, 0, stream>>>((const float4*)W2, (ushort4*)WBIG, (DFF_*D_) / 4);
    k_gemm128<1><<<dim3(M_/128, (DFFP+127)/128), 256, 0, stream>>>(h2b, WBIG, ubuf, ubuf,
                                                                   DFFP, DFF_, D_);
    // 11. x_ff = f @ W3^T   [2048 x 1024], K=DFFP (pad cols zero on both sides)
    k_f2b_pad<<<2048, 256, 0, stream>>>(W3, WBIG, DFF_, DFFP, D_);
    k_gemm128<0><<<dim3(M_/128, D_/128), 256, 0, stream>>>(ubuf, WBIG, xffb, nullptr,
                                                           D_, D_, DFFP);
    // 12. out[b, idx, :] = y + x_ff  (fp32)
    k_scatter<<<M_, 256, 0, stream>>>(ybuf, xffb, idx, out);
}

// Round 13
// 325.404 us; speedup vs baseline: 135.7691x; 1.1947x over previous
//
#include <hip/hip_runtime.h>
#include <hip/hip_bf16.h>

// MoD transformer block: B=4, T=4096, D=1024, H=16, HD=64, CAP=512, DFF=2730
// Inputs fp32, output fp32. Round 13: GEMM retile 128x128 -> 64x128 (BK=64).
// r12 GEMMs were grid-starved: 352/128 blocks on 256 CUs, Occupancy 5.5%,
// MfmaUtil 5%, VALUBusy 2.7% (latency-bound). New grids: 768/704/256 blocks.

#define B_   4
#define T_   4096
#define D_   1024
#define H_   16
#define HD_  64
#define CAP_ 512
#define DFF_ 2730
#define DFFP 2752               // DFF padded to mult of 64 for the BK=64 K-path
#define M_   (B_*CAP_)          // 2048 selected rows total

typedef __attribute__((ext_vector_type(8))) short          s16x8;
typedef __attribute__((ext_vector_type(8))) unsigned short u16x8;
typedef __attribute__((ext_vector_type(4))) float          f32x4;

__device__ __forceinline__ float bf2f(unsigned short u) {
    union { float f; unsigned int i; } v; v.i = ((unsigned int)u) << 16; return v.f;
}
__device__ __forceinline__ unsigned short f2bf(float f) {
    union { float f; unsigned int i; } v; v.f = f;
    unsigned int r = v.i + 0x7fffu + ((v.i >> 16) & 1u);   // RNE
    return (unsigned short)(r >> 16);
}

// ---------------- out = x pass-through (fp32 copy) ----------------
__global__ __launch_bounds__(256) void k_copyf(const float4* __restrict__ s,
                                               float4* __restrict__ d, int n4) {
    int i = blockIdx.x * 256 + threadIdx.x;
    int st = gridDim.x * 256;
    for (; i < n4; i += st) d[i] = s[i];
}

// ---------------- fp32 -> bf16 flat convert ----------------
__global__ __launch_bounds__(256) void k_f2b(const float4* __restrict__ s,
                                             ushort4* __restrict__ d, int n4) {
    int i = blockIdx.x * 256 + threadIdx.x;
    int st = gridDim.x * 256;
    for (; i < n4; i += st) {
        float4 v = s[i];
        ushort4 o;
        o.x = f2bf(v.x); o.y = f2bf(v.y); o.z = f2bf(v.z); o.w = f2bf(v.w);
        d[i] = o;
    }
}

// ---------------- fp32 [rows][K] -> bf16 [rows][Kp], zero-padded cols ----------------
__global__ __launch_bounds__(256) void k_f2b_pad(const float* __restrict__ src,
                                                 unsigned short* __restrict__ dst,
                                                 int K, int Kp, int rows) {
    int g = blockIdx.x * 256 + threadIdx.x;
    int ng = rows * (Kp >> 3);
    int st = gridDim.x * 256;
    for (; g < ng; g += st) {
        int row = g / (Kp >> 3);
        int c = (g - row * (Kp >> 3)) << 3;
        const float* s = src + (size_t)row * K + c;
        u16x8 v;
        if (c + 8 <= K) {
#pragma unroll
            for (int j = 0; j < 4; ++j) {            // 8B-aligned (K,c even)
                float2 f = *(const float2*)(s + 2 * j);
                v[2*j] = f2bf(f.x); v[2*j+1] = f2bf(f.y);
            }
        } else {
#pragma unroll
            for (int j = 0; j < 8; ++j) v[j] = (c + j < K) ? f2bf(s[j]) : (unsigned short)0;
        }
        *(u16x8*)(dst + (size_t)row * Kp + c) = v;
    }
}

// ---------------- router scores: one wave per token row ----------------
__global__ __launch_bounds__(256) void k_router(const float* __restrict__ x,
                                                const float* __restrict__ wr,
                                                float* __restrict__ sc) {
    int gw   = (blockIdx.x * 256 + threadIdx.x) >> 6;   // 0..B*T-1
    int lane = threadIdx.x & 63;
    const float* row = x + (size_t)gw * D_;
    float s = 0.f;
#pragma unroll
    for (int p = 0; p < 4; ++p) {
        int c = p * 256 + lane * 4;
        float4 xv = *(const float4*)(row + c);
        float4 wv = *(const float4*)(wr + c);
        s += xv.x * wv.x + xv.y * wv.y + xv.z * wv.z + xv.w * wv.w;
    }
#pragma unroll
    for (int o = 32; o; o >>= 1) s += __shfl_xor(s, o);
    if (lane == 0) sc[gw] = s;
}

// ---------------- exact top-k: bitonic sort 4096 keys per batch ----------------
__global__ __launch_bounds__(1024) void k_topk(const float* __restrict__ sc,
                                               int* __restrict__ idx) {
    __shared__ unsigned long long keys[T_];
    const float* s = sc + (size_t)blockIdx.x * T_;
    for (int i = threadIdx.x; i < T_; i += 1024) {
        union { float f; unsigned int u; } v; v.f = s[i];
        unsigned int k = (v.u & 0x80000000u) ? ~v.u : (v.u | 0x80000000u);
        k = ~k;
        keys[i] = ((unsigned long long)k << 32) | (unsigned int)i;
    }
    __syncthreads();
    for (int kk = 2; kk <= T_; kk <<= 1) {
        for (int j = kk >> 1; j > 0; j >>= 1) {
            for (int i = threadIdx.x; i < T_; i += 1024) {
                int ixj = i ^ j;
                if (ixj > i) {
                    unsigned long long a = keys[i], b = keys[ixj];
                    bool up = ((i & kk) == 0);
                    if ((a > b) == up) { keys[i] = b; keys[ixj] = a; }
                }
            }
            __syncthreads();
        }
    }
    for (int i = threadIdx.x; i < CAP_; i += 1024)
        idx[blockIdx.x * CAP_ + i] = (int)(keys[i] & 0xffffffffu);
}

// ---------------- gather + RMSNorm(g1) -> h (bf16) ----------------
__global__ __launch_bounds__(256) void k_gather_rms(const float* __restrict__ x,
                                                    const int* __restrict__ idx,
                                                    const float* __restrict__ g,
                                                    unsigned short* __restrict__ h) {
    int r = blockIdx.x;                 // 0..M_-1
    int b = r >> 9;                     // /CAP_
    int src = idx[r] & (T_ - 1);
    const float* xr = x + ((size_t)b * T_ + src) * D_;
    int c = threadIdx.x * 4;
    float4 xv = *(const float4*)(xr + c);
    float ss = xv.x*xv.x + xv.y*xv.y + xv.z*xv.z + xv.w*xv.w;
#pragma unroll
    for (int o = 32; o; o >>= 1) ss += __shfl_xor(ss, o);
    __shared__ float red[4];
    int lane = threadIdx.x & 63, w = threadIdx.x >> 6;
    if (lane == 0) red[w] = ss;
    __syncthreads();
    float tot = red[0] + red[1] + red[2] + red[3];
    float scale = rsqrtf(tot * (1.f / D_) + 1e-6f);
    float4 gv = *(const float4*)(g + c);
    ushort4 hv;
    hv.x = f2bf(xv.x * scale * gv.x);
    hv.y = f2bf(xv.y * scale * gv.y);
    hv.z = f2bf(xv.z * scale * gv.z);
    hv.w = f2bf(xv.w * scale * gv.w);
    *(ushort4*)(h + (size_t)r * D_ + c) = hv;
}

// ---------------- MFMA GEMM 64x128 (BK=64): C[M,Nout] = A[M,Kr] * B[Nb,Kr]^T ----------------
// A, B bf16 (B pre-converted). Kr % 64 == 0. 4 waves split N (each 64x32:
// 4x2 frags, 16 MFMA/K-iter over 2 k-halves). B rows >= Nb stage zero.
// EPI==1: C = silu(U) * acc (U may alias C; 1:1 thread:element).
template<int EPI>
__global__ __launch_bounds__(256) void k_gemm64(const unsigned short* __restrict__ A,
                                                const unsigned short* __restrict__ Bw,
                                                unsigned short* __restrict__ C,
                                                const unsigned short* __restrict__ U,
                                                int Nout, int Nb, int Kr) {
    __shared__ __align__(16) unsigned short As[64][72];    // stride 144B: 2-way banks (free)
    __shared__ __align__(16) unsigned short Bs[128][72];
    int m0 = blockIdx.x * 64;
    int n0 = blockIdx.y * 128;
    int t = threadIdx.x;
    int w = t >> 6, lane = t & 63;
    int lr = lane & 15, lg = lane >> 4;
    int arow = t >> 2, acol = (t & 3) * 16;   // A tile 64x64: 2 chunks/thread
    int brow = t >> 1, bcol = (t & 1) * 32;   // B tile 128x64: 4 chunks/thread

    f32x4 acc[4][2];
#pragma unroll
    for (int mi = 0; mi < 4; ++mi)
#pragma unroll
        for (int ni = 0; ni < 2; ++ni) acc[mi][ni] = {0.f, 0.f, 0.f, 0.f};

    for (int k0 = 0; k0 < Kr; k0 += 64) {
        // stage A (M % 64 == 0: rows in-bounds)
        {
            const unsigned short* ap = A + (size_t)(m0 + arow) * Kr + k0 + acol;
            *(u16x8*)&As[arow][acol]     = *(const u16x8*)ap;
            *(u16x8*)&As[arow][acol + 8] = *(const u16x8*)(ap + 8);
        }
        // stage B (guard Nb)
        {
            const unsigned short* bp = Bw + (size_t)(n0 + brow) * Kr + k0 + bcol;
            bool ok = (n0 + brow < Nb);
#pragma unroll
            for (int j = 0; j < 4; ++j) {
                u16x8 v = {0, 0, 0, 0, 0, 0, 0, 0};
                if (ok) v = *(const u16x8*)(bp + j * 8);
                *(u16x8*)&Bs[brow][bcol + j * 8] = v;
            }
        }
        __syncthreads();
#pragma unroll
        for (int kh = 0; kh < 2; ++kh) {
            s16x8 af[4], bf[2];
#pragma unroll
            for (int i = 0; i < 4; ++i)
                af[i] = *(const s16x8*)&As[i * 16 + lr][kh * 32 + lg * 8];
#pragma unroll
            for (int i = 0; i < 2; ++i)
                bf[i] = *(const s16x8*)&Bs[w * 32 + i * 16 + lr][kh * 32 + lg * 8];
#pragma unroll
            for (int mi = 0; mi < 4; ++mi)
#pragma unroll
                for (int ni = 0; ni < 2; ++ni)
                    acc[mi][ni] = __builtin_amdgcn_mfma_f32_16x16x32_bf16(af[mi], bf[ni],
                                                                          acc[mi][ni], 0, 0, 0);
        }
        __syncthreads();
    }
    // C/D layout: row = (lane>>4)*4 + i, col = lane&15  [measured m89]
    int orow0 = m0 + (lg << 2);
    int ocol0 = n0 + w * 32 + lr;
#pragma unroll
    for (int ni = 0; ni < 2; ++ni) {
        int col = ocol0 + ni * 16;
        if (col < Nout) {
#pragma unroll
            for (int mi = 0; mi < 4; ++mi) {
#pragma unroll
                for (int i = 0; i < 4; ++i) {
                    size_t ci = (size_t)(orow0 + mi * 16 + i) * Nout + col;
                    if (EPI == 1) {
                        float uv = bf2f(U[ci]);
                        float sl = uv / (1.f + __expf(-uv));
                        C[ci] = f2bf(sl * acc[mi][ni][i]);
                    } else {
                        C[ci] = f2bf(acc[mi][ni][i]);
                    }
                }
            }
        }
    }
}

// ---------------- MFMA flash attention (causal, gathered order) ----------------
// One workgroup per (qtile=64, head, batch); 4 waves x 16 q-rows.
__global__ __launch_bounds__(256) void k_attn_mfma(const unsigned short* __restrict__ qkv,
                                                   unsigned short* __restrict__ o) {
    __shared__ __align__(16) unsigned short Ks[32][72];     // [kv][hd 0..63]
    __shared__ __align__(16) unsigned short Vt[64][40];     // [d][kv 0..31]
    __shared__ __align__(16) unsigned short Ps[4][16][40];  // per-wave P [q][kv]
    int qt = blockIdx.x, h = blockIdx.y, b = blockIdx.z;
    int q0 = qt * 64;
    int t = threadIdx.x, w = t >> 6, lane = t & 63;
    int lr = lane & 15, lg = lane >> 4;
    const unsigned short* base = qkv + (size_t)b * CAP_ * 3 * D_;

    int qrow = q0 + w * 16 + lr;
    const unsigned short* qp = base + (size_t)qrow * 3 * D_ + h * 64;
    s16x8 aq0 = *(const s16x8*)(qp + lg * 8);
    s16x8 aq1 = *(const s16x8*)(qp + 32 + lg * 8);

    f32x4 zero = {0.f, 0.f, 0.f, 0.f};
    f32x4 oacc[4] = {zero, zero, zero, zero};
    float m_[4], l_[4];
#pragma unroll
    for (int i = 0; i < 4; ++i) { m_[i] = -3.0e38f; l_[i] = 0.f; }

    int qbase = q0 + w * 16 + lg * 4;
    int ntile = (q0 + 64) >> 5;

    int skv = t >> 3, sc = (t & 7) * 8;
    for (int kt = 0; kt < ntile; ++kt) {
        int kv0 = kt << 5;
        {
            const unsigned short* kr = base + (size_t)(kv0 + skv) * 3 * D_ + D_     + h * 64 + sc;
            const unsigned short* vr = base + (size_t)(kv0 + skv) * 3 * D_ + 2 * D_ + h * 64 + sc;
            *(u16x8*)&Ks[skv][sc] = *(const u16x8*)kr;
            u16x8 vv = *(const u16x8*)vr;
#pragma unroll
            for (int j = 0; j < 8; ++j) Vt[sc + j][skv] = vv[j];
        }
        __syncthreads();
        f32x4 s0 = zero, s1 = zero;
        s16x8 k00 = *(const s16x8*)&Ks[lr][lg * 8];
        s16x8 k01 = *(const s16x8*)&Ks[lr][32 + lg * 8];
        s16x8 k10 = *(const s16x8*)&Ks[16 + lr][lg * 8];
        s16x8 k11 = *(const s16x8*)&Ks[16 + lr][32 + lg * 8];
        s0 = __builtin_amdgcn_mfma_f32_16x16x32_bf16(aq0, k00, s0, 0, 0, 0);
        s0 = __builtin_amdgcn_mfma_f32_16x16x32_bf16(aq1, k01, s0, 0, 0, 0);
        s1 = __builtin_amdgcn_mfma_f32_16x16x32_bf16(aq0, k10, s1, 0, 0, 0);
        s1 = __builtin_amdgcn_mfma_f32_16x16x32_bf16(aq1, k11, s1, 0, 0, 0);
#pragma unroll
        for (int i = 0; i < 4; ++i) {
            float v0 = s0[i] * 0.125f, v1 = s1[i] * 0.125f;
            if (kv0 + lr      > qbase + i) v0 = -3.0e38f;
            if (kv0 + 16 + lr > qbase + i) v1 = -3.0e38f;
            s0[i] = v0; s1[i] = v1;
        }
        float pm[4];
#pragma unroll
        for (int i = 0; i < 4; ++i) pm[i] = fmaxf(s0[i], s1[i]);
#pragma unroll
        for (int d = 1; d < 16; d <<= 1) {
#pragma unroll
            for (int i = 0; i < 4; ++i) pm[i] = fmaxf(pm[i], __shfl_xor(pm[i], d));
        }
        float p0[4], p1[4], ps[4], scl[4];
#pragma unroll
        for (int i = 0; i < 4; ++i) {
            float mn = fmaxf(m_[i], pm[i]);
            scl[i] = __expf(m_[i] - mn);
            p0[i] = __expf(s0[i] - mn);
            p1[i] = __expf(s1[i] - mn);
            ps[i] = p0[i] + p1[i];
            m_[i] = mn;
        }
#pragma unroll
        for (int d = 1; d < 16; d <<= 1) {
#pragma unroll
            for (int i = 0; i < 4; ++i) ps[i] += __shfl_xor(ps[i], d);
        }
#pragma unroll
        for (int i = 0; i < 4; ++i) l_[i] = l_[i] * scl[i] + ps[i];
#pragma unroll
        for (int dg = 0; dg < 4; ++dg)
#pragma unroll
            for (int i = 0; i < 4; ++i) oacc[dg][i] *= scl[i];
#pragma unroll
        for (int i = 0; i < 4; ++i) {
            Ps[w][lg * 4 + i][lr]      = f2bf(p0[i]);
            Ps[w][lg * 4 + i][16 + lr] = f2bf(p1[i]);
        }
        __syncthreads();
        s16x8 pa = *(const s16x8*)&Ps[w][lr][lg * 8];
#pragma unroll
        for (int dg = 0; dg < 4; ++dg) {
            s16x8 vf = *(const s16x8*)&Vt[dg * 16 + lr][lg * 8];
            oacc[dg] = __builtin_amdgcn_mfma_f32_16x16x32_bf16(pa, vf, oacc[dg], 0, 0, 0);
        }
        __syncthreads();
    }
    unsigned short* orow = o + ((size_t)(b * CAP_ + qbase)) * D_ + h * 64;
#pragma unroll
    for (int i = 0; i < 4; ++i) {
        float inv = 1.f / l_[i];
#pragma unroll
        for (int dg = 0; dg < 4; ++dg)
            orow[(size_t)i * D_ + dg * 16 + lr] = f2bf(oacc[dg][i] * inv);
    }
}

// ---------------- y = x_sel + xattn; h2 = rmsnorm(y, g2) ----------------
__global__ __launch_bounds__(256) void k_add_rms(const float* __restrict__ x,
                                                 const int* __restrict__ idx,
                                                 const unsigned short* __restrict__ xattn,
                                                 const float* __restrict__ g,
                                                 unsigned short* __restrict__ y,
                                                 unsigned short* __restrict__ h) {
    int r = blockIdx.x;
    int b = r >> 9;
    int src = idx[r] & (T_ - 1);
    int c = threadIdx.x * 4;
    const float* xr = x + ((size_t)b * T_ + src) * D_;
    float4 xv = *(const float4*)(xr + c);
    size_t off = (size_t)r * D_ + c;
    ushort4 a4 = *(const ushort4*)(xattn + off);
    float v0 = xv.x + bf2f(a4.x);
    float v1 = xv.y + bf2f(a4.y);
    float v2 = xv.z + bf2f(a4.z);
    float v3 = xv.w + bf2f(a4.w);
    float ss = v0*v0 + v1*v1 + v2*v2 + v3*v3;
#pragma unroll
    for (int o = 32; o; o >>= 1) ss += __shfl_xor(ss, o);
    __shared__ float red[4];
    int lane = threadIdx.x & 63, w = threadIdx.x >> 6;
    if (lane == 0) red[w] = ss;
    __syncthreads();
    float tot = red[0] + red[1] + red[2] + red[3];
    float scale = rsqrtf(tot * (1.f / D_) + 1e-6f);
    ushort4 yv;
    yv.x = f2bf(v0); yv.y = f2bf(v1); yv.z = f2bf(v2); yv.w = f2bf(v3);
    *(ushort4*)(y + off) = yv;
    float4 gv = *(const float4*)(g + c);
    ushort4 hv;
    hv.x = f2bf(v0 * scale * gv.x);
    hv.y = f2bf(v1 * scale * gv.y);
    hv.z = f2bf(v2 * scale * gv.z);
    hv.w = f2bf(v3 * scale * gv.w);
    *(ushort4*)(h + off) = hv;
}

// ---------------- scatter: out[b, idx, :] = y + xff  (fp32 out) ----------------
__global__ __launch_bounds__(256) void k_scatter(const unsigned short* __restrict__ y,
                                                 const unsigned short* __restrict__ xff,
                                                 const int* __restrict__ idx,
                                                 float* __restrict__ out) {
    int r = blockIdx.x;
    int b = r >> 9;
    int dst = idx[r] & (T_ - 1);
    int c = threadIdx.x * 4;
    size_t src = (size_t)r * D_ + c;
    ushort4 a4 = *(const ushort4*)(y + src);
    ushort4 f4 = *(const ushort4*)(xff + src);
    float4 o4;
    o4.x = bf2f(a4.x) + bf2f(f4.x);
    o4.y = bf2f(a4.y) + bf2f(f4.y);
    o4.z = bf2f(a4.z) + bf2f(f4.z);
    o4.w = bf2f(a4.w) + bf2f(f4.w);
    *(float4*)(out + ((size_t)b * T_ + dst) * D_ + c) = o4;
}

extern "C" void kernel_launch(void* const* d_in, const int* in_sizes, int n_in,
                              void* d_out, int out_size, void* d_ws, size_t ws_size,
                              hipStream_t stream) {
    const float* x     = (const float*)d_in[0];
    const float* w_rt  = (const float*)d_in[1];
    const float* W_qkv = (const float*)d_in[2];
    const float* W_out = (const float*)d_in[3];
    const float* g1    = (const float*)d_in[4];
    const float* g2    = (const float*)d_in[5];
    const float* W1    = (const float*)d_in[6];
    const float* W2    = (const float*)d_in[7];
    const float* W3    = (const float*)d_in[8];
    float* out = (float*)d_out;

    // ---- workspace: ~31.6 MiB (identical layout to r12) ----
    char* p = (char*)d_ws;
    float* scores = (float*)p;
    int*   idx    = (int*)(p + 65536);
    size_t off = 131072;
    unsigned short* WBIG = (unsigned short*)(p + off); off += (size_t)3*D_*D_*2;   // 6.29M
    unsigned short* R1   = (unsigned short*)(p + off); off += (size_t)M_*3*D_*2;   // 12.58M
    unsigned short* R2   = (unsigned short*)(p + off); off += (size_t)M_*D_*2;     // 4.19M
    unsigned short* R3   = (unsigned short*)(p + off); off += (size_t)M_*D_*2;     // 4.19M
    unsigned short* R4   = (unsigned short*)(p + off); off += (size_t)M_*D_*2;     // 4.19M

    unsigned short* h1    = R2;
    unsigned short* qkvb  = R1;
    unsigned short* attno = R2;   // after h1 dead
    unsigned short* xattn = R3;
    unsigned short* ybuf  = R4;
    unsigned short* h2b   = R2;   // after attno dead
    unsigned short* ubuf  = R1;   // after qkvb dead; [2048][DFFP]
    unsigned short* xffb  = R3;   // after xattn dead

    // 1. out = x  (fp32 pass-through; selected rows overwritten by scatter)
    k_copyf<<<2048, 256, 0, stream>>>((const float4*)x, (float4*)out, (B_*T_*D_) / 4);
    // 2. router scores
    k_router<<<(B_*T_) / 4, 256, 0, stream>>>(x, w_rt, scores);
    // 3. exact top-k
    k_topk<<<B_, 1024, 0, stream>>>(scores, idx);
    // 4. gather + rmsnorm(g1) -> h1 (bf16)
    k_gather_rms<<<M_, 256, 0, stream>>>(x, idx, g1, h1);
    // 5. qkv = h1 @ W_qkv^T   [2048 x 3072], K=1024   (768 blocks)
    k_f2b<<<2048, 256, 0, stream>>>((const float4*)W_qkv, (ushort4*)WBIG, (3*D_*D_) / 4);
    k_gemm64<0><<<dim3(M_/64, 3*D_/128), 256, 0, stream>>>(h1, WBIG, qkvb, nullptr,
                                                           3*D_, 3*D_, D_);
    // 6. MFMA flash attention
    k_attn_mfma<<<dim3(CAP_/64, H_, B_), 256, 0, stream>>>(qkvb, attno);
    // 7. x_attn = o @ W_out^T  [2048 x 1024], K=1024   (256 blocks)
    k_f2b<<<1024, 256, 0, stream>>>((const float4*)W_out, (ushort4*)WBIG, (D_*D_) / 4);
    k_gemm64<0><<<dim3(M_/64, D_/128), 256, 0, stream>>>(attno, WBIG, xattn, nullptr,
                                                         D_, D_, D_);
    // 8. y = x_sel + xattn; h2 = rmsnorm(y, g2)
    k_add_rms<<<M_, 256, 0, stream>>>(x, idx, xattn, g2, ybuf, h2b);
    // 9. u = h2 @ W1^T  -> ubuf [2048][DFFP], pad cols exact zero   (704 blocks)
    k_f2b<<<2048, 256, 0, stream>>>((const float4*)W1, (ushort4*)WBIG, (DFF_*D_) / 4);
    k_gemm64<0><<<dim3(M_/64, (DFFP+127)/128), 256, 0, stream>>>(h2b, WBIG, ubuf, nullptr,
                                                                 DFFP, DFF_, D_);
    // 10. f = silu(u) * (h2 @ W2^T)  — fused epilogue, in-place into ubuf
    k_f2b<<<2048, 256, 0, stream>>>((const float4*)W2, (ushort4*)WBIG, (DFF_*D_) / 4);
    k_gemm64<1><<<dim3(M_/64, (DFFP+127)/128), 256, 0, stream>>>(h2b, WBIG, ubuf, ubuf,
                                                                 DFFP, DFF_, D_);
    // 11. x_ff = f @ W3^T   [2048 x 1024], K=DFFP   (256 blocks)
    k_f2b_pad<<<2048, 256, 0, stream>>>(W3, WBIG, DFF_, DFFP, D_);
    k_gemm64<0><<<dim3(M_/64, D_/128), 256, 0, stream>>>(ubuf, WBIG, xffb, nullptr,
                                                         D_, D_, DFFP);
    // 12. out[b, idx, :] = y + x_ff  (fp32)
    k_scatter<<<M_, 256, 0, stream>>>(ybuf, xffb, idx, out);
}